// Round 1
// baseline (327.180 us; speedup 1.0000x reference)
//
#include <hip/hip_runtime.h>
#include <cstdint>

// ---- types ----
typedef __bf16 bf16x8 __attribute__((ext_vector_type(8)));
typedef float  f32x4  __attribute__((ext_vector_type(4)));
typedef float  float8v __attribute__((ext_vector_type(8)));
typedef unsigned short ushort8v __attribute__((ext_vector_type(8)));

__device__ __forceinline__ unsigned short f2b(float f) {
  uint32_t u = __builtin_bit_cast(uint32_t, f);
  u += 0x7FFFu + ((u >> 16) & 1u);     // round-to-nearest-even
  return (unsigned short)(u >> 16);
}
__device__ __forceinline__ float b2f(unsigned short h) {
  uint32_t u = ((uint32_t)h) << 16;
  return __builtin_bit_cast(float, u);
}

__device__ __forceinline__ void async16(const void* g, void* l) {
  __builtin_amdgcn_global_load_lds(
      (const __attribute__((address_space(1))) void*)g,
      (__attribute__((address_space(3))) void*)l, 16, 0, 0);
}

// ---- fp32 -> bf16 convert (vectorized, grid-stride) ----
__global__ void cvt_kernel(const float* __restrict__ src, unsigned short* __restrict__ dst, long n) {
  long i = ((long)blockIdx.x * blockDim.x + threadIdx.x) * 8;
  long stride = (long)gridDim.x * blockDim.x * 8;
  for (; i < n; i += stride) {
    float8v f = *(const float8v*)(src + i);
    ushort8v o;
#pragma unroll
    for (int j = 0; j < 8; ++j) o[j] = f2b(f[j]);
    *(ushort8v*)(dst + i) = o;
  }
}

// ---- GEMM: C[M][N] = A[M][K] * W[N][K]^T  (bf16 in, bf16 or f32 out) ----
// m97-style: 128x128 tile, 4 waves (2x2), BK=32, global_load_lds staging.
template<bool F32OUT>
__global__ __launch_bounds__(256)
void gemm_bt(const unsigned short* __restrict__ A, const unsigned short* __restrict__ W,
             void* __restrict__ Cp, int M, int N, int K) {
  __shared__ unsigned short lA[128 * 32];
  __shared__ unsigned short lB[128 * 32];
  const int tid = threadIdx.x;
  const int m0 = blockIdx.y * 128, n0 = blockIdx.x * 128;
  const int wave = tid >> 6, lane = tid & 63;
  const int lr = lane & 15, lg = lane >> 4;
  const int wr = wave >> 1, wc = wave & 1;

  f32x4 acc[4][4] = {};

  const int ktiles = K >> 5;
  for (int kt = 0; kt < ktiles; ++kt) {
    const int k0 = kt << 5;
    __syncthreads();
    {
      int flat = tid * 8;                    // issue 0: rows 0..63
      int row = flat >> 5, col = flat & 31;
      async16(A + (size_t)(m0 + row) * K + k0 + col, &lA[flat]);
      async16(W + (size_t)(n0 + row) * K + k0 + col, &lB[flat]);
      flat += 2048; row = flat >> 5; col = flat & 31;   // issue 1: rows 64..127
      async16(A + (size_t)(m0 + row) * K + k0 + col, &lA[flat]);
      async16(W + (size_t)(n0 + row) * K + k0 + col, &lB[flat]);
    }
    __syncthreads();

    bf16x8 af[4], bf[4];
#pragma unroll
    for (int i = 0; i < 4; ++i) {
      af[i] = *(const bf16x8*)&lA[(wr * 64 + i * 16 + lr) * 32 + lg * 8];
      bf[i] = *(const bf16x8*)&lB[(wc * 64 + i * 16 + lr) * 32 + lg * 8];
    }
#pragma unroll
    for (int mi = 0; mi < 4; ++mi)
#pragma unroll
      for (int ni = 0; ni < 4; ++ni)
        acc[mi][ni] = __builtin_amdgcn_mfma_f32_16x16x32_bf16(af[mi], bf[ni], acc[mi][ni], 0, 0, 0);
  }

#pragma unroll
  for (int mi = 0; mi < 4; ++mi) {
#pragma unroll
    for (int j = 0; j < 4; ++j) {
      int row = m0 + wr * 64 + mi * 16 + lg * 4 + j;
#pragma unroll
      for (int ni = 0; ni < 4; ++ni) {
        int col = n0 + wc * 64 + ni * 16 + lr;
        float v = acc[mi][ni][j];
        if (F32OUT) ((float*)Cp)[(size_t)row * N + col] = v;
        else        ((unsigned short*)Cp)[(size_t)row * N + col] = f2b(v);
      }
    }
  }
}

// ---- RoPE in-place on qkv buffer (4096 x 3072): q cols [0,2048), k cols [2048,2560) ----
__global__ void rope_kernel(unsigned short* __restrict__ qkv,
                            const float* __restrict__ cosb, const float* __restrict__ sinb) {
  long idx = (long)blockIdx.x * blockDim.x + threadIdx.x;
  const long total = (long)4096 * 1280;    // 1024 q-pairs + 256 k-pairs per row
  if (idx >= total) return;
  int row = (int)(idx / 1280);
  int p   = (int)(idx % 1280);
  int col0 = (p < 1024) ? (2 * p) : (2048 + 2 * (p - 1024));
  int t  = row & 1023;
  int dp = p & 31;                          // pair index within head (HEAD_DIM/2 = 32)
  float c = cosb[t * 32 + dp], s = sinb[t * 32 + dp];
  unsigned short* base = qkv + (size_t)row * 3072 + col0;
  float x0 = b2f(base[0]), x1 = b2f(base[1]);
  base[0] = f2b(x0 * c - x1 * s);
  base[1] = f2b(x0 * s + x1 * c);
}

// ---- flash attention ----
// grid: (qt=T/16, kvh=8, b=4); 4 waves = 4 reps (heads h=kvh*4+wave), shared K/V LDS.
// K/V tiles 32x64 bf16 in LDS, XOR-swizzled (byte ^= (row&7)<<4) via pre-swizzled
// global_load_lds source. P goes through padded LDS (stride 48) for D->A re-layout.
__global__ __launch_bounds__(256)
void attn_kernel(const unsigned short* __restrict__ qkv, unsigned short* __restrict__ ob) {
  const int qt  = blockIdx.x;
  const int kvh = blockIdx.y;
  const int b   = blockIdx.z;
  const int tid = threadIdx.x;
  const int wave = tid >> 6, lane = tid & 63;
  const int lr = lane & 15, lg = lane >> 4;
  const int q0 = qt * 16;
  const int h  = kvh * 4 + wave;

  __shared__ unsigned short lK[32 * 64];
  __shared__ unsigned short lV[32 * 64];
  __shared__ unsigned short lP[4][16 * 48];   // per-wave, q-stride 48 (96B, 16B-aligned)

  // Q fragments: A[m=q=lr][k=d], d-slices lg*8.. and 32+lg*8..
  const unsigned short* qrow = qkv + (size_t)(b * 1024 + q0 + lr) * 3072 + h * 64;
  bf16x8 qf0 = *(const bf16x8*)(qrow + lg * 8);
  bf16x8 qf1 = *(const bf16x8*)(qrow + 32 + lg * 8);

  float m_run[4], l_run[4];
  f32x4 oacc[4] = {};
#pragma unroll
  for (int j = 0; j < 4; ++j) { m_run[j] = -3e38f; l_run[j] = 0.f; }

  const int ntiles = (q0 + 47) >> 5;
  const unsigned short* kbase = qkv + (size_t)(b * 1024) * 3072 + 2048 + kvh * 64;
  const unsigned short* vbase = kbase + 512;

  const int srow = tid >> 3;                       // staging row 0..31
  const int scol = ((tid & 7) ^ (srow & 7)) * 8;   // pre-swizzled source column

  for (int it = 0; it < ntiles; ++it) {
    const int kvb = it * 32;
    __syncthreads();
    async16(kbase + (size_t)(kvb + srow) * 3072 + scol, &lK[tid * 8]);
    async16(vbase + (size_t)(kvb + srow) * 3072 + scol, &lV[tid * 8]);
    __syncthreads();

    // S = Q K^T : D layout n=kv=c*16+lr, m=q=lg*4+j
    f32x4 sd[2] = {};
#pragma unroll
    for (int c = 0; c < 2; ++c) {
      int krow = c * 16 + lr;
      int xo = (krow & 7) << 4;
      bf16x8 kf0 = *(const bf16x8*)((const char*)lK + krow * 128 + ((lg * 16) ^ xo));
      bf16x8 kf1 = *(const bf16x8*)((const char*)lK + krow * 128 + ((64 + lg * 16) ^ xo));
      sd[c] = __builtin_amdgcn_mfma_f32_16x16x32_bf16(qf0, kf0, sd[c], 0, 0, 0);
      sd[c] = __builtin_amdgcn_mfma_f32_16x16x32_bf16(qf1, kf1, sd[c], 0, 0, 0);
    }

    // mask + scale
    float sv[2][4];
#pragma unroll
    for (int c = 0; c < 2; ++c) {
      int kv = kvb + c * 16 + lr;
#pragma unroll
      for (int j = 0; j < 4; ++j) {
        int q = q0 + lg * 4 + j;
        float s = sd[c][j] * 0.125f;
        sv[c][j] = (kv <= q) ? s : -3e38f;
      }
    }

    // online softmax (row stats across the 16 lanes of each lg-group)
    float tmax[4];
#pragma unroll
    for (int j = 0; j < 4; ++j) tmax[j] = fmaxf(sv[0][j], sv[1][j]);
#pragma unroll
    for (int msk = 1; msk < 16; msk <<= 1)
#pragma unroll
      for (int j = 0; j < 4; ++j) tmax[j] = fmaxf(tmax[j], __shfl_xor(tmax[j], msk));

    float alpha[4];
#pragma unroll
    for (int j = 0; j < 4; ++j) {
      float mnew = fmaxf(m_run[j], tmax[j]);
      alpha[j] = __expf(m_run[j] - mnew);
      m_run[j] = mnew;
    }

    float p[2][4], tsum[4];
#pragma unroll
    for (int j = 0; j < 4; ++j) tsum[j] = 0.f;
#pragma unroll
    for (int c = 0; c < 2; ++c)
#pragma unroll
      for (int j = 0; j < 4; ++j) { p[c][j] = __expf(sv[c][j] - m_run[j]); tsum[j] += p[c][j]; }
#pragma unroll
    for (int msk = 1; msk < 16; msk <<= 1)
#pragma unroll
      for (int j = 0; j < 4; ++j) tsum[j] += __shfl_xor(tsum[j], msk);

#pragma unroll
    for (int j = 0; j < 4; ++j) l_run[j] = l_run[j] * alpha[j] + tsum[j];
#pragma unroll
    for (int nf = 0; nf < 4; ++nf)
#pragma unroll
      for (int j = 0; j < 4; ++j) oacc[nf][j] *= alpha[j];

    // P -> LDS (D layout write), reload as A layout
    unsigned short* lp = &lP[wave][0];
#pragma unroll
    for (int c = 0; c < 2; ++c)
#pragma unroll
      for (int j = 0; j < 4; ++j)
        lp[(lg * 4 + j) * 48 + c * 16 + lr] = f2b(p[c][j]);

    bf16x8 pa = *(const bf16x8*)(lp + lr * 48 + lg * 8);

    // O += P V : B[k=kv=lg*8+i][n=d=nf*16+lr]
#pragma unroll
    for (int nf = 0; nf < 4; ++nf) {
      bf16x8 vf;
#pragma unroll
      for (int i = 0; i < 8; ++i) {
        int vrow = lg * 8 + i;
        int lb = (nf * 16 + lr) * 2;
        vf[i] = *(const __bf16*)((const char*)lV + vrow * 128 + (lb ^ (i << 4)));
      }
      oacc[nf] = __builtin_amdgcn_mfma_f32_16x16x32_bf16(pa, vf, oacc[nf], 0, 0, 0);
    }
  }

  // finalize: ob[(b,t,h,d)] layout (4096 x 2048)
#pragma unroll
  for (int j = 0; j < 4; ++j) {
    float inv = 1.0f / l_run[j];
    size_t rbase = (size_t)(b * 1024 + q0 + lg * 4 + j) * 2048 + h * 64;
#pragma unroll
    for (int nf = 0; nf < 4; ++nf)
      ob[rbase + nf * 16 + lr] = f2b(oacc[nf][j] * inv);
  }
}

extern "C" void kernel_launch(void* const* d_in, const int* in_sizes, int n_in,
                              void* d_out, int out_size, void* d_ws, size_t ws_size,
                              hipStream_t stream) {
  const float* input = (const float*)d_in[0];
  const float* fcos  = (const float*)d_in[1];
  const float* fsin  = (const float*)d_in[2];
  // d_in[3] = mask (causal, implemented analytically); d_in[8] = curr_pos (0)
  const float* wq = (const float*)d_in[4];
  const float* wk = (const float*)d_in[5];
  const float* wv = (const float*)d_in[6];
  const float* wo = (const float*)d_in[7];
  float* out = (float*)d_out;

  // workspace layout (bf16 buffers), total ~79.7 MB
  unsigned short* xb   = (unsigned short*)d_ws;               // 4096 x 2048
  unsigned short* wqkv = xb + (size_t)4096 * 2048;            // 3072 x 2048 (wq|wk|wv rows)
  unsigned short* wob  = wqkv + (size_t)3072 * 2048;          // 2048 x 2048
  unsigned short* qkv  = wob + (size_t)2048 * 2048;           // 4096 x 3072
  unsigned short* ob   = qkv + (size_t)4096 * 3072;           // 4096 x 2048

  auto cvt = [&](const float* s, unsigned short* d, long n) {
    long nb = (n / 8 + 255) / 256;
    int blocks = (int)(nb > 2048 ? 2048 : nb);
    hipLaunchKernelGGL(cvt_kernel, dim3(blocks), dim3(256), 0, stream, s, d, n);
  };
  cvt(input, xb, (long)4096 * 2048);
  cvt(wq, wqkv,                         (long)2048 * 2048);
  cvt(wk, wqkv + (size_t)2048 * 2048,   (long)512 * 2048);
  cvt(wv, wqkv + (size_t)2560 * 2048,   (long)512 * 2048);
  cvt(wo, wob,                          (long)2048 * 2048);

  // fused QKV projection: qkv = xb @ wqkv^T   (M=4096, N=3072, K=2048)
  hipLaunchKernelGGL((gemm_bt<false>), dim3(3072 / 128, 4096 / 128), dim3(256), 0, stream,
                     xb, wqkv, (void*)qkv, 4096, 3072, 2048);

  // RoPE in-place on q + k columns
  hipLaunchKernelGGL(rope_kernel, dim3((4096 * 1280) / 256), dim3(256), 0, stream,
                     qkv, fcos, fsin);

  // flash attention -> ob (b,t,h,d)
  hipLaunchKernelGGL(attn_kernel, dim3(64, 8, 4), dim3(256), 0, stream, qkv, ob);

  // output projection: out = ob @ wob^T  (M=4096, N=2048, K=2048), fp32 out
  hipLaunchKernelGGL((gemm_bt<true>), dim3(2048 / 128, 4096 / 128), dim3(256), 0, stream,
                     ob, wob, (void*)out, 4096, 2048, 2048);
}

// Round 2
// 243.000 us; speedup vs baseline: 1.3464x; 1.3464x over previous
//
#include <hip/hip_runtime.h>
#include <cstdint>

// ---- types ----
typedef __bf16 bf16x8 __attribute__((ext_vector_type(8)));
typedef float  f32x4  __attribute__((ext_vector_type(4)));
typedef float  f32x16 __attribute__((ext_vector_type(16)));
typedef float  float8v __attribute__((ext_vector_type(8)));
typedef unsigned short ushort8v __attribute__((ext_vector_type(8)));
typedef unsigned short ushort4v __attribute__((ext_vector_type(4)));
typedef unsigned int   uint4v   __attribute__((ext_vector_type(4)));

__device__ __forceinline__ unsigned short f2b(float f) {
  uint32_t u = __builtin_bit_cast(uint32_t, f);
  u += 0x7FFFu + ((u >> 16) & 1u);     // round-to-nearest-even
  return (unsigned short)(u >> 16);
}
__device__ __forceinline__ float b2f(unsigned short h) {
  uint32_t u = ((uint32_t)h) << 16;
  return __builtin_bit_cast(float, u);
}
__device__ __forceinline__ unsigned int cvtpk(float lo, float hi_) {
  unsigned int r;
  asm("v_cvt_pk_bf16_f32 %0, %1, %2" : "=v"(r) : "v"(lo), "v"(hi_));
  return r;
}

__device__ __forceinline__ void async16(const void* g, void* l) {
  __builtin_amdgcn_global_load_lds(
      (const __attribute__((address_space(1))) void*)g,
      (__attribute__((address_space(3))) void*)l, 16, 0, 0);
}

// ---- fp32 -> bf16 convert (vectorized, grid-stride) ----
__global__ void cvt_kernel(const float* __restrict__ src, unsigned short* __restrict__ dst, long n) {
  long i = ((long)blockIdx.x * blockDim.x + threadIdx.x) * 8;
  long stride = (long)gridDim.x * blockDim.x * 8;
  for (; i < n; i += stride) {
    float8v f = *(const float8v*)(src + i);
    ushort8v o;
#pragma unroll
    for (int j = 0; j < 8; ++j) o[j] = f2b(f[j]);
    *(ushort8v*)(dst + i) = o;
  }
}

// ---- GEMM: C[M][N] = A[M][K] * W[N][K]^T  (bf16 in, bf16 or f32 out) ----
template<bool F32OUT>
__global__ __launch_bounds__(256)
void gemm_bt(const unsigned short* __restrict__ A, const unsigned short* __restrict__ W,
             void* __restrict__ Cp, int M, int N, int K) {
  __shared__ unsigned short lA[128 * 32];
  __shared__ unsigned short lB[128 * 32];
  const int tid = threadIdx.x;
  const int m0 = blockIdx.y * 128, n0 = blockIdx.x * 128;
  const int wave = tid >> 6, lane = tid & 63;
  const int lr = lane & 15, lg = lane >> 4;
  const int wr = wave >> 1, wc = wave & 1;

  f32x4 acc[4][4] = {};

  const int ktiles = K >> 5;
  for (int kt = 0; kt < ktiles; ++kt) {
    const int k0 = kt << 5;
    __syncthreads();
    {
      int flat = tid * 8;
      int row = flat >> 5, col = flat & 31;
      async16(A + (size_t)(m0 + row) * K + k0 + col, &lA[flat]);
      async16(W + (size_t)(n0 + row) * K + k0 + col, &lB[flat]);
      flat += 2048; row = flat >> 5; col = flat & 31;
      async16(A + (size_t)(m0 + row) * K + k0 + col, &lA[flat]);
      async16(W + (size_t)(n0 + row) * K + k0 + col, &lB[flat]);
    }
    __syncthreads();

    bf16x8 af[4], bfr[4];
#pragma unroll
    for (int i = 0; i < 4; ++i) {
      af[i]  = *(const bf16x8*)&lA[(wr * 64 + i * 16 + lr) * 32 + lg * 8];
      bfr[i] = *(const bf16x8*)&lB[(wc * 64 + i * 16 + lr) * 32 + lg * 8];
    }
#pragma unroll
    for (int mi = 0; mi < 4; ++mi)
#pragma unroll
      for (int ni = 0; ni < 4; ++ni)
        acc[mi][ni] = __builtin_amdgcn_mfma_f32_16x16x32_bf16(af[mi], bfr[ni], acc[mi][ni], 0, 0, 0);
  }

#pragma unroll
  for (int mi = 0; mi < 4; ++mi) {
#pragma unroll
    for (int j = 0; j < 4; ++j) {
      int row = m0 + wr * 64 + mi * 16 + lg * 4 + j;
#pragma unroll
      for (int ni = 0; ni < 4; ++ni) {
        int col = n0 + wc * 64 + ni * 16 + lr;
        float v = acc[mi][ni][j];
        if (F32OUT) ((float*)Cp)[(size_t)row * N + col] = v;
        else        ((unsigned short*)Cp)[(size_t)row * N + col] = f2b(v);
      }
    }
  }
}

// ---- RoPE in-place on qkv buffer (4096 x 3072): q cols [0,2048), k cols [2048,2560) ----
__global__ void rope_kernel(unsigned short* __restrict__ qkv,
                            const float* __restrict__ cosb, const float* __restrict__ sinb) {
  long idx = (long)blockIdx.x * blockDim.x + threadIdx.x;
  const long total = (long)4096 * 1280;
  if (idx >= total) return;
  int row = (int)(idx / 1280);
  int p   = (int)(idx % 1280);
  int col0 = (p < 1024) ? (2 * p) : (2048 + 2 * (p - 1024));
  int t  = row & 1023;
  int dp = p & 31;
  float c = cosb[t * 32 + dp], s = sinb[t * 32 + dp];
  unsigned short* base = qkv + (size_t)row * 3072 + col0;
  float x0 = b2f(base[0]), x1 = b2f(base[1]);
  base[0] = f2b(x0 * c - x1 * s);
  base[1] = f2b(x0 * s + x1 * c);
}

// ---- V transpose: qkv v-cols -> vt[b][kvh][d=64][t=1024] ----
__global__ __launch_bounds__(256)
void vtrans_kernel(const unsigned short* __restrict__ qkv, unsigned short* __restrict__ vt) {
  const int tt0 = blockIdx.x * 64;
  const int kvh = blockIdx.y;
  const int b   = blockIdx.z;
  __shared__ unsigned short lT[64 * 68];
  const int tid = threadIdx.x;
#pragma unroll
  for (int i = 0; i < 2; ++i) {
    int r = i * 32 + (tid >> 3), c = (tid & 7) * 8;
    const unsigned short* src = qkv + (size_t)(b * 1024 + tt0 + r) * 3072 + 2560 + kvh * 64 + c;
    ushort8v v = *(const ushort8v*)src;
    ushort4v a, b4;
#pragma unroll
    for (int j = 0; j < 4; ++j) { a[j] = v[j]; b4[j] = v[j + 4]; }
    *(ushort4v*)&lT[r * 68 + c]     = a;
    *(ushort4v*)&lT[r * 68 + c + 4] = b4;
  }
  __syncthreads();
#pragma unroll
  for (int i = 0; i < 2; ++i) {
    int d = tid & 63;
    int tt = i * 4 + (tid >> 6);
    ushort8v o;
#pragma unroll
    for (int j = 0; j < 8; ++j) o[j] = lT[(tt * 8 + j) * 68 + d];
    *(ushort8v*)&vt[((size_t)((b * 8 + kvh) * 64 + d)) * 1024 + tt0 + tt * 8] = o;
  }
}

// ---- flash attention, swapped-operand 32x32 MFMA ----
// grid (T/32=32, KVH=8, B=4), 4 waves = 4 reps sharing K/Vt LDS. KVBLK=64.
__global__ __launch_bounds__(256)
void attn_kernel(const unsigned short* __restrict__ qkv, const unsigned short* __restrict__ vt,
                 unsigned short* __restrict__ ob) {
  const int qt = blockIdx.x, kvh = blockIdx.y, b = blockIdx.z;
  const int tid = threadIdx.x, wave = tid >> 6, lane = tid & 63;
  const int l31 = lane & 31, hi = lane >> 5;
  const int q0 = qt * 32;
  const int h = kvh * 4 + wave;

  __shared__ unsigned short lK[64 * 64];
  __shared__ unsigned short lVt[64 * 64];

  // Q fragments: B[k=d][n=q]: lane holds Q[q0+l31][dk*16 + hi*8 + i]
  bf16x8 qf[4];
  const unsigned short* qp = qkv + (size_t)(b * 1024 + q0 + l31) * 3072 + h * 64;
#pragma unroll
  for (int dk = 0; dk < 4; ++dk) qf[dk] = *(const bf16x8*)(qp + dk * 16 + hi * 8);

  f32x16 oacc[2] = {};
  float m2 = -3e38f, l_run = 0.f;

  const int nt = qt / 2 + 1;
  const unsigned short* kg = qkv + (size_t)(b * 1024) * 3072 + 2048 + kvh * 64;
  const unsigned short* vg = vt + (size_t)(b * 8 + kvh) * 64 * 1024;

  const int sr  = tid >> 3;          // 0..31
  const int scb = (tid & 7) * 16;    // dest col byte

  for (int it = 0; it < nt; ++it) {
    const int kvb = it * 64;
    __syncthreads();
#pragma unroll
    for (int i = 0; i < 2; ++i) {
      int r = i * 32 + sr;
      int cb = scb ^ ((r & 7) << 4);          // pre-swizzled source col byte
      async16(kg + (size_t)(kvb + r) * 3072 + (cb >> 1), &lK[r * 64 + (scb >> 1)]);
      async16(vg + (size_t)r * 1024 + kvb + (cb >> 1), &lVt[r * 64 + (scb >> 1)]);
    }
    __syncthreads();

    // S^T = K Q^T : D col = q = l31, row r -> kv = (r&3)+8*(r>>2)+4*hi
    f32x16 sd[2] = {};
#pragma unroll
    for (int s = 0; s < 2; ++s) {
      const int krow = s * 32 + l31;
      const char* kr = (const char*)lK + krow * 128;
      const int swz = (krow & 7) << 4;
#pragma unroll
      for (int dk = 0; dk < 4; ++dk) {
        bf16x8 kf = *(const bf16x8*)(kr + ((dk * 32 + hi * 16) ^ swz));
        sd[s] = __builtin_amdgcn_mfma_f32_32x32x16_bf16(kf, qf[dk], sd[s], 0, 0, 0);
      }
    }

    // scale (pre-multiplied by log2e; exp2 below) + causal mask on last tile
    const float SC = 0.125f * 1.44269504f;
    const bool last = (it == nt - 1);
#pragma unroll
    for (int s = 0; s < 2; ++s)
#pragma unroll
      for (int r = 0; r < 16; ++r) {
        float v = sd[s][r] * SC;
        if (last) {
          int kvg = kvb + s * 32 + (r & 3) + 8 * (r >> 2) + 4 * hi;
          if (kvg > q0 + l31) v = -3e38f;
        }
        sd[s][r] = v;
      }

    // online softmax, lane-local for q = l31
    float pm = sd[0][0];
#pragma unroll
    for (int s = 0; s < 2; ++s)
#pragma unroll
      for (int r = 0; r < 16; ++r) pm = fmaxf(pm, sd[s][r]);
    pm = fmaxf(pm, __shfl_xor(pm, 32));
    float mnew = fmaxf(m2, pm);
    float alpha = exp2f(m2 - mnew);
    m2 = mnew;
    float tsum = 0.f;
#pragma unroll
    for (int s = 0; s < 2; ++s)
#pragma unroll
      for (int r = 0; r < 16; ++r) { float p = exp2f(sd[s][r] - mnew); sd[s][r] = p; tsum += p; }
    tsum += __shfl_xor(tsum, 32);
    l_run = l_run * alpha + tsum;
#pragma unroll
    for (int db = 0; db < 2; ++db)
#pragma unroll
      for (int r = 0; r < 16; ++r) oacc[db][r] *= alpha;

    // P fragments in-register: cvt_pk pairs + permlane32-swap (emulated)
    bf16x8 pfrag[2][2];
#pragma unroll
    for (int s = 0; s < 2; ++s)
#pragma unroll
      for (int kc = 0; kc < 2; ++kc) {
        unsigned int cA = cvtpk(sd[s][8 * kc + 0], sd[s][8 * kc + 1]);
        unsigned int cB = cvtpk(sd[s][8 * kc + 4], sd[s][8 * kc + 5]);
        unsigned int cC = cvtpk(sd[s][8 * kc + 2], sd[s][8 * kc + 3]);
        unsigned int cD = cvtpk(sd[s][8 * kc + 6], sd[s][8 * kc + 7]);
        unsigned int xA = __shfl_xor(cA, 32), xB = __shfl_xor(cB, 32);
        unsigned int xC = __shfl_xor(cC, 32), xD = __shfl_xor(cD, 32);
        uint4v u;
        u[0] = hi ? xB : cA;
        u[1] = hi ? xD : cC;
        u[2] = hi ? cB : xA;
        u[3] = hi ? cD : xC;
        pfrag[s][kc] = __builtin_bit_cast(bf16x8, u);
      }

    // O^T += V^T P^T : A = Vt-frag, B = P-frag; D col = q = l31, row -> d
#pragma unroll
    for (int db = 0; db < 2; ++db) {
      const char* vr = (const char*)lVt + (db * 32 + l31) * 128;
      const int vswz = (l31 & 7) << 4;
#pragma unroll
      for (int s = 0; s < 2; ++s)
#pragma unroll
        for (int kc = 0; kc < 2; ++kc) {
          bf16x8 vf = *(const bf16x8*)(vr + ((s * 64 + kc * 32 + hi * 16) ^ vswz));
          oacc[db] = __builtin_amdgcn_mfma_f32_32x32x16_bf16(vf, pfrag[s][kc], oacc[db], 0, 0, 0);
        }
    }
  }

  // epilogue: O^T row r -> d = (r&3)+8*(r>>2)+4*hi, col = q = l31
  float inv = 1.0f / l_run;
  unsigned short* orow = ob + (size_t)(b * 1024 + q0 + l31) * 2048 + h * 64;
#pragma unroll
  for (int db = 0; db < 2; ++db)
#pragma unroll
    for (int g = 0; g < 4; ++g) {
      int d0 = db * 32 + 8 * g + 4 * hi;
      ushort4v o;
#pragma unroll
      for (int j = 0; j < 4; ++j) o[j] = f2b(oacc[db][4 * g + j] * inv);
      *(ushort4v*)(orow + d0) = o;
    }
}

extern "C" void kernel_launch(void* const* d_in, const int* in_sizes, int n_in,
                              void* d_out, int out_size, void* d_ws, size_t ws_size,
                              hipStream_t stream) {
  const float* input = (const float*)d_in[0];
  const float* fcos  = (const float*)d_in[1];
  const float* fsin  = (const float*)d_in[2];
  const float* wq = (const float*)d_in[4];
  const float* wk = (const float*)d_in[5];
  const float* wv = (const float*)d_in[6];
  const float* wo = (const float*)d_in[7];
  float* out = (float*)d_out;

  unsigned short* xb   = (unsigned short*)d_ws;               // 4096 x 2048 (dead after gemm1)
  unsigned short* wqkv = xb + (size_t)4096 * 2048;            // 3072 x 2048
  unsigned short* wob  = wqkv + (size_t)3072 * 2048;          // 2048 x 2048
  unsigned short* qkv  = wob + (size_t)2048 * 2048;           // 4096 x 3072
  unsigned short* ob   = qkv + (size_t)4096 * 3072;           // 4096 x 2048
  unsigned short* vtb  = xb;                                  // 4*8*64*1024 (reuses xb)

  auto cvt = [&](const float* s, unsigned short* d, long n) {
    long nb = (n / 8 + 255) / 256;
    int blocks = (int)(nb > 2048 ? 2048 : nb);
    hipLaunchKernelGGL(cvt_kernel, dim3(blocks), dim3(256), 0, stream, s, d, n);
  };
  cvt(input, xb, (long)4096 * 2048);
  cvt(wq, wqkv,                         (long)2048 * 2048);
  cvt(wk, wqkv + (size_t)2048 * 2048,   (long)512 * 2048);
  cvt(wv, wqkv + (size_t)2560 * 2048,   (long)512 * 2048);
  cvt(wo, wob,                          (long)2048 * 2048);

  hipLaunchKernelGGL((gemm_bt<false>), dim3(3072 / 128, 4096 / 128), dim3(256), 0, stream,
                     xb, wqkv, (void*)qkv, 4096, 3072, 2048);

  hipLaunchKernelGGL(rope_kernel, dim3((4096 * 1280) / 256), dim3(256), 0, stream,
                     qkv, fcos, fsin);

  hipLaunchKernelGGL(vtrans_kernel, dim3(16, 8, 4), dim3(256), 0, stream, qkv, vtb);

  hipLaunchKernelGGL(attn_kernel, dim3(32, 8, 4), dim3(256), 0, stream, qkv, vtb, ob);

  hipLaunchKernelGGL((gemm_bt<true>), dim3(2048 / 128, 4096 / 128), dim3(256), 0, stream,
                     ob, wob, (void*)out, 4096, 2048, 2048);
}

// Round 3
// 215.907 us; speedup vs baseline: 1.5154x; 1.1255x over previous
//
#include <hip/hip_runtime.h>
#include <cstdint>

// ---- types ----
typedef __bf16 bf16x8 __attribute__((ext_vector_type(8)));
typedef float  f32x4  __attribute__((ext_vector_type(4)));
typedef float  f32x16 __attribute__((ext_vector_type(16)));
typedef float  float8v __attribute__((ext_vector_type(8)));
typedef unsigned short ushort8v __attribute__((ext_vector_type(8)));
typedef unsigned short ushort4v __attribute__((ext_vector_type(4)));
typedef unsigned int   uint4v   __attribute__((ext_vector_type(4)));

__device__ __forceinline__ unsigned short f2b(float f) {
  uint32_t u = __builtin_bit_cast(uint32_t, f);
  u += 0x7FFFu + ((u >> 16) & 1u);     // round-to-nearest-even
  return (unsigned short)(u >> 16);
}
__device__ __forceinline__ float b2f(unsigned short h) {
  uint32_t u = ((uint32_t)h) << 16;
  return __builtin_bit_cast(float, u);
}
__device__ __forceinline__ unsigned int cvtpk(float lo, float hi_) {
  unsigned int r;
  asm("v_cvt_pk_bf16_f32 %0, %1, %2" : "=v"(r) : "v"(lo), "v"(hi_));
  return r;
}

__device__ __forceinline__ void async16(const void* g, void* l) {
  __builtin_amdgcn_global_load_lds(
      (const __attribute__((address_space(1))) void*)g,
      (__attribute__((address_space(3))) void*)l, 16, 0, 0);
}

// ---- fp32 -> bf16 convert (vectorized, grid-stride) ----
__global__ void cvt_kernel(const float* __restrict__ src, unsigned short* __restrict__ dst, long n) {
  long i = ((long)blockIdx.x * blockDim.x + threadIdx.x) * 8;
  long stride = (long)gridDim.x * blockDim.x * 8;
  for (; i < n; i += stride) {
    float8v f = *(const float8v*)(src + i);
    ushort8v o;
#pragma unroll
    for (int j = 0; j < 8; ++j) o[j] = f2b(f[j]);
    *(ushort8v*)(dst + i) = o;
  }
}

// ---- GEMM: C[M][N] = A[M][K] * W[N][K]^T  (bf16 in, bf16 or f32 out) ----
template<bool F32OUT>
__global__ __launch_bounds__(256)
void gemm_bt(const unsigned short* __restrict__ A, const unsigned short* __restrict__ W,
             void* __restrict__ Cp, int M, int N, int K) {
  __shared__ unsigned short lA[128 * 32];
  __shared__ unsigned short lB[128 * 32];
  const int tid = threadIdx.x;
  const int m0 = blockIdx.y * 128, n0 = blockIdx.x * 128;
  const int wave = tid >> 6, lane = tid & 63;
  const int lr = lane & 15, lg = lane >> 4;
  const int wr = wave >> 1, wc = wave & 1;

  f32x4 acc[4][4] = {};

  const int ktiles = K >> 5;
  for (int kt = 0; kt < ktiles; ++kt) {
    const int k0 = kt << 5;
    __syncthreads();
    {
      int flat = tid * 8;
      int row = flat >> 5, col = flat & 31;
      async16(A + (size_t)(m0 + row) * K + k0 + col, &lA[flat]);
      async16(W + (size_t)(n0 + row) * K + k0 + col, &lB[flat]);
      flat += 2048; row = flat >> 5; col = flat & 31;
      async16(A + (size_t)(m0 + row) * K + k0 + col, &lA[flat]);
      async16(W + (size_t)(n0 + row) * K + k0 + col, &lB[flat]);
    }
    __syncthreads();

    bf16x8 af[4], bfr[4];
#pragma unroll
    for (int i = 0; i < 4; ++i) {
      af[i]  = *(const bf16x8*)&lA[(wr * 64 + i * 16 + lr) * 32 + lg * 8];
      bfr[i] = *(const bf16x8*)&lB[(wc * 64 + i * 16 + lr) * 32 + lg * 8];
    }
#pragma unroll
    for (int mi = 0; mi < 4; ++mi)
#pragma unroll
      for (int ni = 0; ni < 4; ++ni)
        acc[mi][ni] = __builtin_amdgcn_mfma_f32_16x16x32_bf16(af[mi], bfr[ni], acc[mi][ni], 0, 0, 0);
  }

#pragma unroll
  for (int mi = 0; mi < 4; ++mi) {
#pragma unroll
    for (int j = 0; j < 4; ++j) {
      int row = m0 + wr * 64 + mi * 16 + lg * 4 + j;
#pragma unroll
      for (int ni = 0; ni < 4; ++ni) {
        int col = n0 + wc * 64 + ni * 16 + lr;
        float v = acc[mi][ni][j];
        if (F32OUT) ((float*)Cp)[(size_t)row * N + col] = v;
        else        ((unsigned short*)Cp)[(size_t)row * N + col] = f2b(v);
      }
    }
  }
}

// ---- RoPE in-place on qkv buffer (4096 x 3072): q cols [0,2048), k cols [2048,2560) ----
__global__ void rope_kernel(unsigned short* __restrict__ qkv,
                            const float* __restrict__ cosb, const float* __restrict__ sinb) {
  long idx = (long)blockIdx.x * blockDim.x + threadIdx.x;
  const long total = (long)4096 * 1280;
  if (idx >= total) return;
  int row = (int)(idx / 1280);
  int p   = (int)(idx % 1280);
  int col0 = (p < 1024) ? (2 * p) : (2048 + 2 * (p - 1024));
  int t  = row & 1023;
  int dp = p & 31;
  float c = cosb[t * 32 + dp], s = sinb[t * 32 + dp];
  unsigned short* base = qkv + (size_t)row * 3072 + col0;
  float x0 = b2f(base[0]), x1 = b2f(base[1]);
  base[0] = f2b(x0 * c - x1 * s);
  base[1] = f2b(x0 * s + x1 * c);
}

// ---- V transpose: qkv v-cols -> vt[b][kvh][d=64][t=1024] ----
__global__ __launch_bounds__(256)
void vtrans_kernel(const unsigned short* __restrict__ qkv, unsigned short* __restrict__ vt) {
  const int tt0 = blockIdx.x * 64;
  const int kvh = blockIdx.y;
  const int b   = blockIdx.z;
  __shared__ unsigned short lT[64 * 68];
  const int tid = threadIdx.x;
#pragma unroll
  for (int i = 0; i < 2; ++i) {
    int r = i * 32 + (tid >> 3), c = (tid & 7) * 8;
    const unsigned short* src = qkv + (size_t)(b * 1024 + tt0 + r) * 3072 + 2560 + kvh * 64 + c;
    ushort8v v = *(const ushort8v*)src;
    ushort4v a, b4;
#pragma unroll
    for (int j = 0; j < 4; ++j) { a[j] = v[j]; b4[j] = v[j + 4]; }
    *(ushort4v*)&lT[r * 68 + c]     = a;
    *(ushort4v*)&lT[r * 68 + c + 4] = b4;
  }
  __syncthreads();
#pragma unroll
  for (int i = 0; i < 2; ++i) {
    int d = tid & 63;
    int tt = i * 4 + (tid >> 6);
    ushort8v o;
#pragma unroll
    for (int j = 0; j < 8; ++j) o[j] = lT[(tt * 8 + j) * 68 + d];
    *(ushort8v*)&vt[((size_t)((b * 8 + kvh) * 64 + d)) * 1024 + tt0 + tt * 8] = o;
  }
}

// ---- flash attention, swapped-operand 32x32 MFMA, paired q-tiles ----
// grid (16, KVH=8, B=4); block handles q-tiles qt_hi=31-bx and qt_lo=bx for the
// same (b,kvh): constant 17 tile-computations/block, shared K/V staging
// (lo's kv range is a strict subset of hi's). Double-buffered LDS, issue-early
// staging (T14), setprio around MFMA (T5), defer-max rescale (T13).
__global__ __launch_bounds__(256, 2)
void attn_kernel(const unsigned short* __restrict__ qkv, const unsigned short* __restrict__ vt,
                 unsigned short* __restrict__ ob) {
  const int bx = blockIdx.x, kvh = blockIdx.y, b = blockIdx.z;
  const int tid = threadIdx.x, wave = tid >> 6, lane = tid & 63;
  const int l31 = lane & 31, hi = lane >> 5;
  const int h = kvh * 4 + wave;

  const int qth = 31 - bx, qtl = bx;
  const int q0h = qth * 32, q0l = qtl * 32;
  const int nth = qth / 2 + 1, ntl = qtl / 2 + 1;

  __shared__ unsigned short lK[2][64 * 64];
  __shared__ unsigned short lVt[2][64 * 64];

  // Q fragments: B[k=d][n=q]: lane holds Q[q0+l31][dk*16 + hi*8 + i]
  bf16x8 qfh[4], qfl[4];
  {
    const unsigned short* qph = qkv + (size_t)(b * 1024 + q0h + l31) * 3072 + h * 64;
    const unsigned short* qpl = qkv + (size_t)(b * 1024 + q0l + l31) * 3072 + h * 64;
#pragma unroll
    for (int dk = 0; dk < 4; ++dk) {
      qfh[dk] = *(const bf16x8*)(qph + dk * 16 + hi * 8);
      qfl[dk] = *(const bf16x8*)(qpl + dk * 16 + hi * 8);
    }
  }

  f32x16 oh[2] = {}, ol[2] = {};
  float mh = -3e38f, lh = 0.f, ml = -3e38f, ll = 0.f;

  const unsigned short* kg = qkv + (size_t)(b * 1024) * 3072 + 2048 + kvh * 64;
  const unsigned short* vg = vt + (size_t)(b * 8 + kvh) * 64 * 1024;

  const int sr  = tid >> 3;          // 0..31
  const int scb = (tid & 7) * 16;    // dest col byte

  auto stage = [&](int it, int bi) {
    const int kvb = it * 64;
#pragma unroll
    for (int i = 0; i < 2; ++i) {
      int r = i * 32 + sr;
      int cb = scb ^ ((r & 7) << 4);          // pre-swizzled source col byte
      async16(kg + (size_t)(kvb + r) * 3072 + (cb >> 1), &lK[bi][r * 64 + (scb >> 1)]);
      async16(vg + (size_t)r * 1024 + kvb + (cb >> 1), &lVt[bi][r * 64 + (scb >> 1)]);
    }
  };

  // softmax + P-frag build for one q-state (all indices compile-time)
  const float SC = 0.125f * 1.44269504f;
  auto softmax = [&](f32x16 (&sd)[2], float& m2, float& l_run, f32x16 (&oacc)[2],
                     int q0, bool last, int kvb, bf16x8 (&pfrag)[2][2]) {
#pragma unroll
    for (int s = 0; s < 2; ++s)
#pragma unroll
      for (int r = 0; r < 16; ++r) {
        float v = sd[s][r] * SC;
        if (last) {
          int kvg = kvb + s * 32 + (r & 3) + 8 * (r >> 2) + 4 * hi;
          if (kvg > q0 + l31) v = -3e38f;
        }
        sd[s][r] = v;
      }
    float pm = sd[0][0];
#pragma unroll
    for (int s = 0; s < 2; ++s)
#pragma unroll
      for (int r = 0; r < 16; ++r) pm = fmaxf(pm, sd[s][r]);
    pm = fmaxf(pm, __shfl_xor(pm, 32));
    if (!__all(pm <= m2 + 11.0f)) {          // T13 defer-max (log2 domain)
      float mnew = fmaxf(m2, pm);
      float alpha = exp2f(m2 - mnew);
      m2 = mnew;
      l_run *= alpha;
#pragma unroll
      for (int db = 0; db < 2; ++db)
#pragma unroll
        for (int r = 0; r < 16; ++r) oacc[db][r] *= alpha;
    }
    float tsum = 0.f;
#pragma unroll
    for (int s = 0; s < 2; ++s)
#pragma unroll
      for (int r = 0; r < 16; ++r) { float p = exp2f(sd[s][r] - m2); sd[s][r] = p; tsum += p; }
    tsum += __shfl_xor(tsum, 32);
    l_run += tsum;
    // P fragments: cvt_pk pairs + permlane32-swap (emulated)
#pragma unroll
    for (int s = 0; s < 2; ++s)
#pragma unroll
      for (int kc = 0; kc < 2; ++kc) {
        unsigned int cA = cvtpk(sd[s][8 * kc + 0], sd[s][8 * kc + 1]);
        unsigned int cB = cvtpk(sd[s][8 * kc + 4], sd[s][8 * kc + 5]);
        unsigned int cC = cvtpk(sd[s][8 * kc + 2], sd[s][8 * kc + 3]);
        unsigned int cD = cvtpk(sd[s][8 * kc + 6], sd[s][8 * kc + 7]);
        unsigned int xA = __shfl_xor(cA, 32), xB = __shfl_xor(cB, 32);
        unsigned int xC = __shfl_xor(cC, 32), xD = __shfl_xor(cD, 32);
        uint4v u;
        u[0] = hi ? xB : cA;
        u[1] = hi ? xD : cC;
        u[2] = hi ? cB : xA;
        u[3] = hi ? cD : xC;
        pfrag[s][kc] = __builtin_bit_cast(bf16x8, u);
      }
  };

  stage(0, 0);
  __syncthreads();

  for (int it = 0; it < nth; ++it) {
    const int cur = it & 1;
    if (it + 1 < nth) stage(it + 1, cur ^ 1);   // issue-early: hides under compute
    const bool lo_on = (it < ntl);
    const int kvb = it * 64;

    // S^T = K Q^T : D col = q = l31, row r -> kv = (r&3)+8*(r>>2)+4*hi
    f32x16 sh[2] = {}, sl[2] = {};
    __builtin_amdgcn_s_setprio(1);
#pragma unroll
    for (int s = 0; s < 2; ++s) {
      const int krow = s * 32 + l31;
      const char* kr = (const char*)lK[cur] + krow * 128;
      const int swz = (krow & 7) << 4;
#pragma unroll
      for (int dk = 0; dk < 4; ++dk) {
        bf16x8 kf = *(const bf16x8*)(kr + ((dk * 32 + hi * 16) ^ swz));
        sh[s] = __builtin_amdgcn_mfma_f32_32x32x16_bf16(kf, qfh[dk], sh[s], 0, 0, 0);
      }
    }
    if (lo_on) {
#pragma unroll
      for (int s = 0; s < 2; ++s) {
        const int krow = s * 32 + l31;
        const char* kr = (const char*)lK[cur] + krow * 128;
        const int swz = (krow & 7) << 4;
#pragma unroll
        for (int dk = 0; dk < 4; ++dk) {
          bf16x8 kf = *(const bf16x8*)(kr + ((dk * 32 + hi * 16) ^ swz));
          sl[s] = __builtin_amdgcn_mfma_f32_32x32x16_bf16(kf, qfl[dk], sl[s], 0, 0, 0);
        }
      }
    }
    __builtin_amdgcn_s_setprio(0);

    bf16x8 pfh[2][2], pfl[2][2];
    softmax(sh, mh, lh, oh, q0h, it == nth - 1, kvb, pfh);
    if (lo_on) softmax(sl, ml, ll, ol, q0l, it == ntl - 1, kvb, pfl);

    // O^T += V^T P^T : A = Vt-frag, B = P-frag; D col = q = l31, row -> d
    __builtin_amdgcn_s_setprio(1);
#pragma unroll
    for (int db = 0; db < 2; ++db) {
      const char* vr = (const char*)lVt[cur] + (db * 32 + l31) * 128;
      const int vswz = (l31 & 7) << 4;
#pragma unroll
      for (int s = 0; s < 2; ++s)
#pragma unroll
        for (int kc = 0; kc < 2; ++kc) {
          bf16x8 vf = *(const bf16x8*)(vr + ((s * 64 + kc * 32 + hi * 16) ^ vswz));
          oh[db] = __builtin_amdgcn_mfma_f32_32x32x16_bf16(vf, pfh[s][kc], oh[db], 0, 0, 0);
        }
    }
    if (lo_on) {
#pragma unroll
      for (int db = 0; db < 2; ++db) {
        const char* vr = (const char*)lVt[cur] + (db * 32 + l31) * 128;
        const int vswz = (l31 & 7) << 4;
#pragma unroll
        for (int s = 0; s < 2; ++s)
#pragma unroll
          for (int kc = 0; kc < 2; ++kc) {
            bf16x8 vf = *(const bf16x8*)(vr + ((s * 64 + kc * 32 + hi * 16) ^ vswz));
            ol[db] = __builtin_amdgcn_mfma_f32_32x32x16_bf16(vf, pfl[s][kc], ol[db], 0, 0, 0);
          }
      }
    }
    __builtin_amdgcn_s_setprio(0);

    __syncthreads();   // drains prefetch (vmcnt 0) + buffer handoff
  }

  // epilogue: O^T row r -> d = (r&3)+8*(r>>2)+4*hi, col = q = l31
  {
    float inv = 1.0f / lh;
    unsigned short* orow = ob + (size_t)(b * 1024 + q0h + l31) * 2048 + h * 64;
#pragma unroll
    for (int db = 0; db < 2; ++db)
#pragma unroll
      for (int g = 0; g < 4; ++g) {
        int d0 = db * 32 + 8 * g + 4 * hi;
        ushort4v o;
#pragma unroll
        for (int j = 0; j < 4; ++j) o[j] = f2b(oh[db][4 * g + j] * inv);
        *(ushort4v*)(orow + d0) = o;
      }
  }
  {
    float inv = 1.0f / ll;
    unsigned short* orow = ob + (size_t)(b * 1024 + q0l + l31) * 2048 + h * 64;
#pragma unroll
    for (int db = 0; db < 2; ++db)
#pragma unroll
      for (int g = 0; g < 4; ++g) {
        int d0 = db * 32 + 8 * g + 4 * hi;
        ushort4v o;
#pragma unroll
        for (int j = 0; j < 4; ++j) o[j] = f2b(ol[db][4 * g + j] * inv);
        *(ushort4v*)(orow + d0) = o;
      }
  }
}

extern "C" void kernel_launch(void* const* d_in, const int* in_sizes, int n_in,
                              void* d_out, int out_size, void* d_ws, size_t ws_size,
                              hipStream_t stream) {
  const float* input = (const float*)d_in[0];
  const float* fcos  = (const float*)d_in[1];
  const float* fsin  = (const float*)d_in[2];
  const float* wq = (const float*)d_in[4];
  const float* wk = (const float*)d_in[5];
  const float* wv = (const float*)d_in[6];
  const float* wo = (const float*)d_in[7];
  float* out = (float*)d_out;

  unsigned short* xb   = (unsigned short*)d_ws;               // 4096 x 2048 (dead after gemm1)
  unsigned short* wqkv = xb + (size_t)4096 * 2048;            // 3072 x 2048
  unsigned short* wob  = wqkv + (size_t)3072 * 2048;          // 2048 x 2048
  unsigned short* qkv  = wob + (size_t)2048 * 2048;           // 4096 x 3072
  unsigned short* ob   = qkv + (size_t)4096 * 3072;           // 4096 x 2048
  unsigned short* vtb  = xb;                                  // 4*8*64*1024 (reuses xb)

  auto cvt = [&](const float* s, unsigned short* d, long n) {
    long nb = (n / 8 + 255) / 256;
    int blocks = (int)(nb > 2048 ? 2048 : nb);
    hipLaunchKernelGGL(cvt_kernel, dim3(blocks), dim3(256), 0, stream, s, d, n);
  };
  cvt(input, xb, (long)4096 * 2048);
  cvt(wq, wqkv,                         (long)2048 * 2048);
  cvt(wk, wqkv + (size_t)2048 * 2048,   (long)512 * 2048);
  cvt(wv, wqkv + (size_t)2560 * 2048,   (long)512 * 2048);
  cvt(wo, wob,                          (long)2048 * 2048);

  hipLaunchKernelGGL((gemm_bt<false>), dim3(3072 / 128, 4096 / 128), dim3(256), 0, stream,
                     xb, wqkv, (void*)qkv, 4096, 3072, 2048);

  hipLaunchKernelGGL(rope_kernel, dim3((4096 * 1280) / 256), dim3(256), 0, stream,
                     qkv, fcos, fsin);

  hipLaunchKernelGGL(vtrans_kernel, dim3(16, 8, 4), dim3(256), 0, stream, qkv, vtb);

  hipLaunchKernelGGL(attn_kernel, dim3(16, 8, 4), dim3(256), 0, stream, qkv, vtb, ob);

  hipLaunchKernelGGL((gemm_bt<true>), dim3(2048 / 128, 4096 / 128), dim3(256), 0, stream,
                     ob, wob, (void*)out, 4096, 2048, 2048);
}

// Round 4
// 187.106 us; speedup vs baseline: 1.7486x; 1.1539x over previous
//
#include <hip/hip_runtime.h>
#include <cstdint>

// ---- types ----
typedef __bf16 bf16x8 __attribute__((ext_vector_type(8)));
typedef float  f32x4  __attribute__((ext_vector_type(4)));
typedef float  f32x16 __attribute__((ext_vector_type(16)));
typedef float  float8v __attribute__((ext_vector_type(8)));
typedef unsigned short ushort8v __attribute__((ext_vector_type(8)));
typedef unsigned short ushort4v __attribute__((ext_vector_type(4)));
typedef unsigned int   uint4v   __attribute__((ext_vector_type(4)));

__device__ __forceinline__ unsigned short f2b(float f) {
  uint32_t u = __builtin_bit_cast(uint32_t, f);
  u += 0x7FFFu + ((u >> 16) & 1u);     // round-to-nearest-even
  return (unsigned short)(u >> 16);
}
__device__ __forceinline__ float b2f(unsigned short h) {
  uint32_t u = ((uint32_t)h) << 16;
  return __builtin_bit_cast(float, u);
}
__device__ __forceinline__ unsigned int cvtpk(float lo, float hi_) {
  unsigned int r;
  asm("v_cvt_pk_bf16_f32 %0, %1, %2" : "=v"(r) : "v"(lo), "v"(hi_));
  return r;
}

__device__ __forceinline__ void async16(const void* g, void* l) {
  __builtin_amdgcn_global_load_lds(
      (const __attribute__((address_space(1))) void*)g,
      (__attribute__((address_space(3))) void*)l, 16, 0, 0);
}

// s_waitcnt immediates (gfx9 encoding): vmcnt[3:0]|[15:14], expcnt[6:4], lgkmcnt[11:8]
#define WAITVM(N)  __builtin_amdgcn_s_waitcnt(0x0F70 | ((N) & 15))
#define WAITLGKM0  __builtin_amdgcn_s_waitcnt(0xC07F)

// ---- fp32 -> bf16 convert (vectorized, grid-stride) ----
__global__ void cvt_kernel(const float* __restrict__ src, unsigned short* __restrict__ dst, long n) {
  long i = ((long)blockIdx.x * blockDim.x + threadIdx.x) * 8;
  long stride = (long)gridDim.x * blockDim.x * 8;
  for (; i < n; i += stride) {
    float8v f = *(const float8v*)(src + i);
    ushort8v o;
#pragma unroll
    for (int j = 0; j < 8; ++j) o[j] = f2b(f[j]);
    *(ushort8v*)(dst + i) = o;
  }
}

// ---- 8-phase 256-row GEMM: C[M][N] = A[M][K] * W[N][K]^T, K=2048 fixed ----
// BM=256, BK=64, 8 waves (2m x 4n), 512 threads. K-half subtiled staging ring
// of 8 slots (strict double buffer), counted vmcnt (T4), LDS XOR swizzle (T2),
// setprio around MFMA (T5). See round-3 derivation for the schedule proof.
template<bool F32OUT, int BN>
__global__ __launch_bounds__(512, 1)
void gemm8p(const unsigned short* __restrict__ Ag, const unsigned short* __restrict__ Wg,
            void* __restrict__ Cp, int M, int N) {
  constexpr int K = 2048;
  constexpr int NF = BN / 64;        // n-frags per wave (4 or 2)
  constexpr int BL = BN / 128;       // B-half loads per thread (2 or 1)
  constexpr int VN = 4 + 2 * BL;     // steady-state vmcnt (8 or 6)
  constexpr int VT1 = (BN == 256) ? 6 : 4;
  constexpr int VT2 = (BN == 256) ? 4 : 3;
  constexpr int VT3 = (BN == 256) ? 2 : 1;
  constexpr int ASLOT = 16384;       // 256 rows x 32 k x 2B
  constexpr int BSLOT = BN * 64;     // BN rows x 32 k x 2B

  extern __shared__ char lds_c[];

  const int tid = threadIdx.x;
  const int wave = tid >> 6, lane = tid & 63;
  const int wm = wave >> 2, wn = wave & 3;
  const int lr = lane & 15, lg = lane >> 4;
  const int m0 = blockIdx.y * 256, n0 = blockIdx.x * BN;

  // swizzled per-lane byte offset within a slot (macro-row R=lr>>1, group XOR)
  const int laneSw = (lr >> 1) * 128 + (((((lr & 1) << 2) | lg) ^ (lr >> 1)) << 4);
  const int aoff = wm * 8192 + laneSw;
  const int boff = wn * NF * 1024 + laneSw;

  f32x4 acc[8][NF] = {};

  // stage one half-tile of stream index s (consumption order: A.k0,B.k0,A.k1,B.k1 per K-tile)
  auto stageHT = [&](int s) {
    const int ty = s & 3;
    const int kh = (s >> 1) & 1;
    const int buf = (s >> 2) & 1;
    const int kc = (s >> 2) * 64 + kh * 32;
    if (ty == 0 || ty == 2) {
      char* slot = lds_c + (buf * 2 + kh) * ASLOT;
#pragma unroll
      for (int j = 0; j < 2; ++j) {
        int q = (tid + 512 * j) * 16;
        int R = q >> 7, g2L = ((q >> 4) & 7) ^ (R & 7);
        int row = R * 2 + (g2L >> 2), kg = g2L & 3;
        async16(Ag + (size_t)(m0 + row) * K + kc + kg * 8, slot + q);
      }
    } else {
      char* slot = lds_c + 65536 + (buf * 2 + kh) * BSLOT;
#pragma unroll
      for (int j = 0; j < BL; ++j) {
        int q = (tid + 512 * j) * 16;
        int R = q >> 7, g2L = ((q >> 4) & 7) ^ (R & 7);
        int row = R * 2 + (g2L >> 2), kg = g2L & 3;
        async16(Wg + (size_t)(n0 + row) * K + kc + kg * 8, slot + q);
      }
    }
  };

#define PHASE(BUF, KH, MH, VM, ...)                                           \
  {                                                                           \
    const char* As_ = lds_c + ((BUF) * 2 + (KH)) * ASLOT;                     \
    const char* Bs_ = lds_c + 65536 + ((BUF) * 2 + (KH)) * BSLOT;             \
    bf16x8 af_[4], bf_[NF];                                                   \
    _Pragma("unroll") for (int mi = 0; mi < 4; ++mi)                          \
      af_[mi] = *(const bf16x8*)(As_ + aoff + (MH) * 4096 + mi * 1024);       \
    _Pragma("unroll") for (int ni = 0; ni < NF; ++ni)                         \
      bf_[ni] = *(const bf16x8*)(Bs_ + boff + ni * 1024);                     \
    __VA_ARGS__;                                                              \
    WAITVM(VM);                                                               \
    __builtin_amdgcn_s_barrier();                                             \
    WAITLGKM0;                                                                \
    __builtin_amdgcn_sched_barrier(0);                                        \
    __builtin_amdgcn_s_setprio(1);                                            \
    _Pragma("unroll") for (int mi = 0; mi < 4; ++mi)                          \
      _Pragma("unroll") for (int ni = 0; ni < NF; ++ni)                       \
        acc[(MH) * 4 + mi][ni] = __builtin_amdgcn_mfma_f32_16x16x32_bf16(     \
            af_[mi], bf_[ni], acc[(MH) * 4 + mi][ni], 0, 0, 0);               \
    __builtin_amdgcn_s_setprio(0);                                            \
    __builtin_amdgcn_s_barrier();                                             \
  }

  // prologue: stage S[0..5], gate on S[0],S[1]
#pragma unroll
  for (int s = 0; s < 6; ++s) stageHT(s);
  WAITVM(VN);
  __builtin_amdgcn_s_barrier();

#pragma unroll 2
  for (int kt = 0; kt < 30; ++kt) {
    const int buf = kt & 1;
    const int s0 = kt * 4 + 6;
    PHASE(buf, 0, 0, VN, stageHT(s0));
    PHASE(buf, 0, 1, VN, stageHT(s0 + 1));
    PHASE(buf, 1, 0, VN, stageHT(s0 + 2));
    PHASE(buf, 1, 1, VN, stageHT(s0 + 3));
  }
  // kt = 30 (buf 0): last two stages, then drain
  PHASE(0, 0, 0, VN, stageHT(126));
  PHASE(0, 0, 1, VN, stageHT(127));
  PHASE(0, 1, 0, VT1, (void)0);
  PHASE(0, 1, 1, VT2, (void)0);
  // kt = 31 (buf 1)
  PHASE(1, 0, 0, VT3, (void)0);
  PHASE(1, 0, 1, 0, (void)0);
  PHASE(1, 1, 0, 0, (void)0);
  PHASE(1, 1, 1, 0, (void)0);
#undef PHASE

  // epilogue: C/D layout col=lane&15, row=(lane>>4)*4+j
#pragma unroll
  for (int mig = 0; mig < 8; ++mig) {
#pragma unroll
    for (int j = 0; j < 4; ++j) {
      int row = m0 + wm * 128 + mig * 16 + lg * 4 + j;
#pragma unroll
      for (int ni = 0; ni < NF; ++ni) {
        int col = n0 + wn * (NF * 16) + ni * 16 + lr;
        float v = acc[mig][ni][j];
        if (F32OUT) ((float*)Cp)[(size_t)row * N + col] = v;
        else        ((unsigned short*)Cp)[(size_t)row * N + col] = f2b(v);
      }
    }
  }
}

// ---- RoPE in-place on qkv buffer (4096 x 3072): q cols [0,2048), k cols [2048,2560) ----
__global__ void rope_kernel(unsigned short* __restrict__ qkv,
                            const float* __restrict__ cosb, const float* __restrict__ sinb) {
  long idx = (long)blockIdx.x * blockDim.x + threadIdx.x;
  const long total = (long)4096 * 1280;
  if (idx >= total) return;
  int row = (int)(idx / 1280);
  int p   = (int)(idx % 1280);
  int col0 = (p < 1024) ? (2 * p) : (2048 + 2 * (p - 1024));
  int t  = row & 1023;
  int dp = p & 31;
  float c = cosb[t * 32 + dp], s = sinb[t * 32 + dp];
  unsigned short* base = qkv + (size_t)row * 3072 + col0;
  float x0 = b2f(base[0]), x1 = b2f(base[1]);
  base[0] = f2b(x0 * c - x1 * s);
  base[1] = f2b(x0 * s + x1 * c);
}

// ---- V transpose: qkv v-cols -> vt[b][kvh][d=64][t=1024] ----
__global__ __launch_bounds__(256)
void vtrans_kernel(const unsigned short* __restrict__ qkv, unsigned short* __restrict__ vt) {
  const int tt0 = blockIdx.x * 64;
  const int kvh = blockIdx.y;
  const int b   = blockIdx.z;
  __shared__ unsigned short lT[64 * 68];
  const int tid = threadIdx.x;
#pragma unroll
  for (int i = 0; i < 2; ++i) {
    int r = i * 32 + (tid >> 3), c = (tid & 7) * 8;
    const unsigned short* src = qkv + (size_t)(b * 1024 + tt0 + r) * 3072 + 2560 + kvh * 64 + c;
    ushort8v v = *(const ushort8v*)src;
    ushort4v a, b4;
#pragma unroll
    for (int j = 0; j < 4; ++j) { a[j] = v[j]; b4[j] = v[j + 4]; }
    *(ushort4v*)&lT[r * 68 + c]     = a;
    *(ushort4v*)&lT[r * 68 + c + 4] = b4;
  }
  __syncthreads();
#pragma unroll
  for (int i = 0; i < 2; ++i) {
    int d = tid & 63;
    int tt = i * 4 + (tid >> 6);
    ushort8v o;
#pragma unroll
    for (int j = 0; j < 8; ++j) o[j] = lT[(tt * 8 + j) * 68 + d];
    *(ushort8v*)&vt[((size_t)((b * 8 + kvh) * 64 + d)) * 1024 + tt0 + tt * 8] = o;
  }
}

// ---- flash attention, swapped-operand 32x32 MFMA, paired q-tiles ----
__global__ __launch_bounds__(256, 2)
void attn_kernel(const unsigned short* __restrict__ qkv, const unsigned short* __restrict__ vt,
                 unsigned short* __restrict__ ob) {
  const int bx = blockIdx.x, kvh = blockIdx.y, b = blockIdx.z;
  const int tid = threadIdx.x, wave = tid >> 6, lane = tid & 63;
  const int l31 = lane & 31, hi = lane >> 5;
  const int h = kvh * 4 + wave;

  const int qth = 31 - bx, qtl = bx;
  const int q0h = qth * 32, q0l = qtl * 32;
  const int nth = qth / 2 + 1, ntl = qtl / 2 + 1;

  __shared__ unsigned short lK[2][64 * 64];
  __shared__ unsigned short lVt[2][64 * 64];

  bf16x8 qfh[4], qfl[4];
  {
    const unsigned short* qph = qkv + (size_t)(b * 1024 + q0h + l31) * 3072 + h * 64;
    const unsigned short* qpl = qkv + (size_t)(b * 1024 + q0l + l31) * 3072 + h * 64;
#pragma unroll
    for (int dk = 0; dk < 4; ++dk) {
      qfh[dk] = *(const bf16x8*)(qph + dk * 16 + hi * 8);
      qfl[dk] = *(const bf16x8*)(qpl + dk * 16 + hi * 8);
    }
  }

  f32x16 oh[2] = {}, ol[2] = {};
  float mh = -3e38f, lh = 0.f, ml = -3e38f, ll = 0.f;

  const unsigned short* kg = qkv + (size_t)(b * 1024) * 3072 + 2048 + kvh * 64;
  const unsigned short* vg = vt + (size_t)(b * 8 + kvh) * 64 * 1024;

  const int sr  = tid >> 3;
  const int scb = (tid & 7) * 16;

  auto stage = [&](int it, int bi) {
    const int kvb = it * 64;
#pragma unroll
    for (int i = 0; i < 2; ++i) {
      int r = i * 32 + sr;
      int cb = scb ^ ((r & 7) << 4);
      async16(kg + (size_t)(kvb + r) * 3072 + (cb >> 1), &lK[bi][r * 64 + (scb >> 1)]);
      async16(vg + (size_t)r * 1024 + kvb + (cb >> 1), &lVt[bi][r * 64 + (scb >> 1)]);
    }
  };

  const float SC = 0.125f * 1.44269504f;
  auto softmax = [&](f32x16 (&sd)[2], float& m2, float& l_run, f32x16 (&oacc)[2],
                     int q0, bool last, int kvb, bf16x8 (&pfrag)[2][2]) {
#pragma unroll
    for (int s = 0; s < 2; ++s)
#pragma unroll
      for (int r = 0; r < 16; ++r) {
        float v = sd[s][r] * SC;
        if (last) {
          int kvg = kvb + s * 32 + (r & 3) + 8 * (r >> 2) + 4 * hi;
          if (kvg > q0 + l31) v = -3e38f;
        }
        sd[s][r] = v;
      }
    float pm = sd[0][0];
#pragma unroll
    for (int s = 0; s < 2; ++s)
#pragma unroll
      for (int r = 0; r < 16; ++r) pm = fmaxf(pm, sd[s][r]);
    pm = fmaxf(pm, __shfl_xor(pm, 32));
    if (!__all(pm <= m2 + 11.0f)) {
      float mnew = fmaxf(m2, pm);
      float alpha = exp2f(m2 - mnew);
      m2 = mnew;
      l_run *= alpha;
#pragma unroll
      for (int db = 0; db < 2; ++db)
#pragma unroll
        for (int r = 0; r < 16; ++r) oacc[db][r] *= alpha;
    }
    float tsum = 0.f;
#pragma unroll
    for (int s = 0; s < 2; ++s)
#pragma unroll
      for (int r = 0; r < 16; ++r) { float p = exp2f(sd[s][r] - m2); sd[s][r] = p; tsum += p; }
    tsum += __shfl_xor(tsum, 32);
    l_run += tsum;
#pragma unroll
    for (int s = 0; s < 2; ++s)
#pragma unroll
      for (int kc = 0; kc < 2; ++kc) {
        unsigned int cA = cvtpk(sd[s][8 * kc + 0], sd[s][8 * kc + 1]);
        unsigned int cB = cvtpk(sd[s][8 * kc + 4], sd[s][8 * kc + 5]);
        unsigned int cC = cvtpk(sd[s][8 * kc + 2], sd[s][8 * kc + 3]);
        unsigned int cD = cvtpk(sd[s][8 * kc + 6], sd[s][8 * kc + 7]);
        unsigned int xA = __shfl_xor(cA, 32), xB = __shfl_xor(cB, 32);
        unsigned int xC = __shfl_xor(cC, 32), xD = __shfl_xor(cD, 32);
        uint4v u;
        u[0] = hi ? xB : cA;
        u[1] = hi ? xD : cC;
        u[2] = hi ? cB : xA;
        u[3] = hi ? cD : xC;
        pfrag[s][kc] = __builtin_bit_cast(bf16x8, u);
      }
  };

  stage(0, 0);
  __syncthreads();

  for (int it = 0; it < nth; ++it) {
    const int cur = it & 1;
    if (it + 1 < nth) stage(it + 1, cur ^ 1);
    const bool lo_on = (it < ntl);
    const int kvb = it * 64;

    f32x16 sh[2] = {}, sl[2] = {};
    __builtin_amdgcn_s_setprio(1);
#pragma unroll
    for (int s = 0; s < 2; ++s) {
      const int krow = s * 32 + l31;
      const char* kr = (const char*)lK[cur] + krow * 128;
      const int swz = (krow & 7) << 4;
#pragma unroll
      for (int dk = 0; dk < 4; ++dk) {
        bf16x8 kf = *(const bf16x8*)(kr + ((dk * 32 + hi * 16) ^ swz));
        sh[s] = __builtin_amdgcn_mfma_f32_32x32x16_bf16(kf, qfh[dk], sh[s], 0, 0, 0);
      }
    }
    if (lo_on) {
#pragma unroll
      for (int s = 0; s < 2; ++s) {
        const int krow = s * 32 + l31;
        const char* kr = (const char*)lK[cur] + krow * 128;
        const int swz = (krow & 7) << 4;
#pragma unroll
        for (int dk = 0; dk < 4; ++dk) {
          bf16x8 kf = *(const bf16x8*)(kr + ((dk * 32 + hi * 16) ^ swz));
          sl[s] = __builtin_amdgcn_mfma_f32_32x32x16_bf16(kf, qfl[dk], sl[s], 0, 0, 0);
        }
      }
    }
    __builtin_amdgcn_s_setprio(0);

    bf16x8 pfh[2][2], pfl[2][2];
    softmax(sh, mh, lh, oh, q0h, it == nth - 1, kvb, pfh);
    if (lo_on) softmax(sl, ml, ll, ol, q0l, it == ntl - 1, kvb, pfl);

    __builtin_amdgcn_s_setprio(1);
#pragma unroll
    for (int db = 0; db < 2; ++db) {
      const char* vr = (const char*)lVt[cur] + (db * 32 + l31) * 128;
      const int vswz = (l31 & 7) << 4;
#pragma unroll
      for (int s = 0; s < 2; ++s)
#pragma unroll
        for (int kc = 0; kc < 2; ++kc) {
          bf16x8 vf = *(const bf16x8*)(vr + ((s * 64 + kc * 32 + hi * 16) ^ vswz));
          oh[db] = __builtin_amdgcn_mfma_f32_32x32x16_bf16(vf, pfh[s][kc], oh[db], 0, 0, 0);
        }
    }
    if (lo_on) {
#pragma unroll
      for (int db = 0; db < 2; ++db) {
        const char* vr = (const char*)lVt[cur] + (db * 32 + l31) * 128;
        const int vswz = (l31 & 7) << 4;
#pragma unroll
        for (int s = 0; s < 2; ++s)
#pragma unroll
          for (int kc = 0; kc < 2; ++kc) {
            bf16x8 vf = *(const bf16x8*)(vr + ((s * 64 + kc * 32 + hi * 16) ^ vswz));
            ol[db] = __builtin_amdgcn_mfma_f32_32x32x16_bf16(vf, pfl[s][kc], ol[db], 0, 0, 0);
          }
      }
    }
    __builtin_amdgcn_s_setprio(0);

    __syncthreads();
  }

  {
    float inv = 1.0f / lh;
    unsigned short* orow = ob + (size_t)(b * 1024 + q0h + l31) * 2048 + h * 64;
#pragma unroll
    for (int db = 0; db < 2; ++db)
#pragma unroll
      for (int g = 0; g < 4; ++g) {
        int d0 = db * 32 + 8 * g + 4 * hi;
        ushort4v o;
#pragma unroll
        for (int j = 0; j < 4; ++j) o[j] = f2b(oh[db][4 * g + j] * inv);
        *(ushort4v*)(orow + d0) = o;
      }
  }
  {
    float inv = 1.0f / ll;
    unsigned short* orow = ob + (size_t)(b * 1024 + q0l + l31) * 2048 + h * 64;
#pragma unroll
    for (int db = 0; db < 2; ++db)
#pragma unroll
      for (int g = 0; g < 4; ++g) {
        int d0 = db * 32 + 8 * g + 4 * hi;
        ushort4v o;
#pragma unroll
        for (int j = 0; j < 4; ++j) o[j] = f2b(ol[db][4 * g + j] * inv);
        *(ushort4v*)(orow + d0) = o;
      }
  }
}

extern "C" void kernel_launch(void* const* d_in, const int* in_sizes, int n_in,
                              void* d_out, int out_size, void* d_ws, size_t ws_size,
                              hipStream_t stream) {
  const float* input = (const float*)d_in[0];
  const float* fcos  = (const float*)d_in[1];
  const float* fsin  = (const float*)d_in[2];
  const float* wq = (const float*)d_in[4];
  const float* wk = (const float*)d_in[5];
  const float* wv = (const float*)d_in[6];
  const float* wo = (const float*)d_in[7];
  float* out = (float*)d_out;

  unsigned short* xb   = (unsigned short*)d_ws;               // 4096 x 2048 (dead after gemm1)
  unsigned short* wqkv = xb + (size_t)4096 * 2048;            // 3072 x 2048
  unsigned short* wob  = wqkv + (size_t)3072 * 2048;          // 2048 x 2048
  unsigned short* qkv  = wob + (size_t)2048 * 2048;           // 4096 x 3072
  unsigned short* ob   = qkv + (size_t)4096 * 3072;           // 4096 x 2048
  unsigned short* vtb  = xb;                                  // 4*8*64*1024 (reuses xb)

  hipFuncSetAttribute((const void*)&gemm8p<false, 256>,
                      hipFuncAttributeMaxDynamicSharedMemorySize, 131072);
  hipFuncSetAttribute((const void*)&gemm8p<true, 128>,
                      hipFuncAttributeMaxDynamicSharedMemorySize, 98304);

  auto cvt = [&](const float* s, unsigned short* d, long n) {
    long nb = (n / 8 + 255) / 256;
    int blocks = (int)(nb > 2048 ? 2048 : nb);
    hipLaunchKernelGGL(cvt_kernel, dim3(blocks), dim3(256), 0, stream, s, d, n);
  };
  cvt(input, xb, (long)4096 * 2048);
  cvt(wq, wqkv,                         (long)2048 * 2048);
  cvt(wk, wqkv + (size_t)2048 * 2048,   (long)512 * 2048);
  cvt(wv, wqkv + (size_t)2560 * 2048,   (long)512 * 2048);
  cvt(wo, wob,                          (long)2048 * 2048);

  // fused QKV projection: qkv = xb @ wqkv^T  (M=4096, N=3072, K=2048)
  hipLaunchKernelGGL((gemm8p<false, 256>), dim3(3072 / 256, 4096 / 256), dim3(512), 131072,
                     stream, xb, wqkv, (void*)qkv, 4096, 3072);

  hipLaunchKernelGGL(rope_kernel, dim3((4096 * 1280) / 256), dim3(256), 0, stream,
                     qkv, fcos, fsin);

  hipLaunchKernelGGL(vtrans_kernel, dim3(16, 8, 4), dim3(256), 0, stream, qkv, vtb);

  hipLaunchKernelGGL(attn_kernel, dim3(16, 8, 4), dim3(256), 0, stream, qkv, vtb, ob);

  // output projection: out = ob @ wob^T  (M=4096, N=2048, K=2048), fp32 out
  hipLaunchKernelGGL((gemm8p<true, 128>), dim3(2048 / 128, 4096 / 256), dim3(512), 98304,
                     stream, ob, wob, (void*)out, 4096, 2048);
}

// Round 5
// 185.319 us; speedup vs baseline: 1.7655x; 1.0096x over previous
//
#include <hip/hip_runtime.h>
#include <cstdint>

// ---- types ----
typedef __bf16 bf16x8 __attribute__((ext_vector_type(8)));
typedef float  f32x4  __attribute__((ext_vector_type(4)));
typedef float  f32x16 __attribute__((ext_vector_type(16)));
typedef float  float8v __attribute__((ext_vector_type(8)));
typedef unsigned short ushort8v __attribute__((ext_vector_type(8)));
typedef unsigned short ushort4v __attribute__((ext_vector_type(4)));
typedef unsigned int   uint4v   __attribute__((ext_vector_type(4)));

__device__ __forceinline__ unsigned short f2b(float f) {
  uint32_t u = __builtin_bit_cast(uint32_t, f);
  u += 0x7FFFu + ((u >> 16) & 1u);     // round-to-nearest-even
  return (unsigned short)(u >> 16);
}
__device__ __forceinline__ float b2f(unsigned short h) {
  uint32_t u = ((uint32_t)h) << 16;
  return __builtin_bit_cast(float, u);
}
__device__ __forceinline__ unsigned int cvtpk(float lo, float hi_) {
  unsigned int r;
  asm("v_cvt_pk_bf16_f32 %0, %1, %2" : "=v"(r) : "v"(lo), "v"(hi_));
  return r;
}

__device__ __forceinline__ void async16(const void* g, void* l) {
  __builtin_amdgcn_global_load_lds(
      (const __attribute__((address_space(1))) void*)g,
      (__attribute__((address_space(3))) void*)l, 16, 0, 0);
}

// s_waitcnt immediates (gfx9 encoding): vmcnt[3:0]|[15:14], expcnt[6:4], lgkmcnt[11:8]
#define WAITVM(N)  __builtin_amdgcn_s_waitcnt(0x0F70 | ((N) & 15))
#define WAITLGKM0  __builtin_amdgcn_s_waitcnt(0xC07F)

// ---- fused fp32 -> bf16 convert, 5 segments in one launch ----
struct CvtArgs {
  const float* src[5];
  unsigned short* dst[5];
  long n[5];
};
__global__ void cvt5_kernel(CvtArgs a) {
  long base = (long)blockIdx.x * blockDim.x + threadIdx.x;
  long gstride = (long)gridDim.x * blockDim.x;
#pragma unroll 1
  for (int sg = 0; sg < 5; ++sg) {
    const float* s = a.src[sg];
    unsigned short* d = a.dst[sg];
    long n8 = a.n[sg] >> 3;
    for (long i = base; i < n8; i += gstride) {
      float8v f = *(const float8v*)(s + i * 8);
      ushort8v o;
#pragma unroll
      for (int j = 0; j < 8; ++j) o[j] = f2b(f[j]);
      *(ushort8v*)(d + i * 8) = o;
    }
  }
}

// ---- 8-phase 256-row GEMM: C[M][N] = A[M][K] * W[N][K]^T, K=2048, M=4096 ----
// BM=256, BK=64, 8 waves (2m x 4n), 512 threads. K-half staging ring (8 slots),
// counted vmcnt (T4), LDS XOR swizzle (T2), setprio (T5), chunked XCD swizzle (T1):
// each XCD gets 2 m-rows x GX n-cols -> A panels L2-resident.
template<bool F32OUT, int BN, int GX>
__global__ __launch_bounds__(512, 1)
void gemm8p(const unsigned short* __restrict__ Ag, const unsigned short* __restrict__ Wg,
            void* __restrict__ Cp, int M, int N) {
  constexpr int K = 2048;
  constexpr int NF = BN / 64;
  constexpr int BL = BN / 128;
  constexpr int VN = 4 + 2 * BL;
  constexpr int VT1 = (BN == 256) ? 6 : 4;
  constexpr int VT2 = (BN == 256) ? 4 : 3;
  constexpr int VT3 = (BN == 256) ? 2 : 1;
  constexpr int ASLOT = 16384;
  constexpr int BSLOT = BN * 64;
  constexpr int CPX = 2 * GX;         // blocks per XCD chunk (GY=16)

  extern __shared__ char lds_c[];

  const int tid = threadIdx.x;
  const int wave = tid >> 6, lane = tid & 63;
  const int wm = wave >> 2, wn = wave & 3;
  const int lr = lane & 15, lg = lane >> 4;

  // T1: chunked bijective XCD swizzle (nwg = 16*GX, divisible by 8)
  const int flat = blockIdx.y * GX + blockIdx.x;
  const int swz = (flat & 7) * CPX + (flat >> 3);
  const int m0 = (swz / GX) * 256, n0 = (swz % GX) * BN;

  const int laneSw = (lr >> 1) * 128 + (((((lr & 1) << 2) | lg) ^ (lr >> 1)) << 4);
  const int aoff = wm * 8192 + laneSw;
  const int boff = wn * NF * 1024 + laneSw;

  f32x4 acc[8][NF] = {};

  auto stageHT = [&](int s) {
    const int ty = s & 3;
    const int kh = (s >> 1) & 1;
    const int buf = (s >> 2) & 1;
    const int kc = (s >> 2) * 64 + kh * 32;
    if (ty == 0 || ty == 2) {
      char* slot = lds_c + (buf * 2 + kh) * ASLOT;
#pragma unroll
      for (int j = 0; j < 2; ++j) {
        int q = (tid + 512 * j) * 16;
        int R = q >> 7, g2L = ((q >> 4) & 7) ^ (R & 7);
        int row = R * 2 + (g2L >> 2), kg = g2L & 3;
        async16(Ag + (size_t)(m0 + row) * K + kc + kg * 8, slot + q);
      }
    } else {
      char* slot = lds_c + 65536 + (buf * 2 + kh) * BSLOT;
#pragma unroll
      for (int j = 0; j < BL; ++j) {
        int q = (tid + 512 * j) * 16;
        int R = q >> 7, g2L = ((q >> 4) & 7) ^ (R & 7);
        int row = R * 2 + (g2L >> 2), kg = g2L & 3;
        async16(Wg + (size_t)(n0 + row) * K + kc + kg * 8, slot + q);
      }
    }
  };

#define PHASE(BUF, KH, MH, VM, ...)                                           \
  {                                                                           \
    const char* As_ = lds_c + ((BUF) * 2 + (KH)) * ASLOT;                     \
    const char* Bs_ = lds_c + 65536 + ((BUF) * 2 + (KH)) * BSLOT;             \
    bf16x8 af_[4], bf_[NF];                                                   \
    _Pragma("unroll") for (int mi = 0; mi < 4; ++mi)                          \
      af_[mi] = *(const bf16x8*)(As_ + aoff + (MH) * 4096 + mi * 1024);       \
    _Pragma("unroll") for (int ni = 0; ni < NF; ++ni)                         \
      bf_[ni] = *(const bf16x8*)(Bs_ + boff + ni * 1024);                     \
    __VA_ARGS__;                                                              \
    WAITVM(VM);                                                               \
    __builtin_amdgcn_s_barrier();                                             \
    WAITLGKM0;                                                                \
    __builtin_amdgcn_sched_barrier(0);                                        \
    __builtin_amdgcn_s_setprio(1);                                            \
    _Pragma("unroll") for (int mi = 0; mi < 4; ++mi)                          \
      _Pragma("unroll") for (int ni = 0; ni < NF; ++ni)                       \
        acc[(MH) * 4 + mi][ni] = __builtin_amdgcn_mfma_f32_16x16x32_bf16(     \
            af_[mi], bf_[ni], acc[(MH) * 4 + mi][ni], 0, 0, 0);               \
    __builtin_amdgcn_s_setprio(0);                                            \
    __builtin_amdgcn_s_barrier();                                             \
  }

#pragma unroll
  for (int s = 0; s < 6; ++s) stageHT(s);
  WAITVM(VN);
  __builtin_amdgcn_s_barrier();

#pragma unroll 2
  for (int kt = 0; kt < 30; ++kt) {
    const int buf = kt & 1;
    const int s0 = kt * 4 + 6;
    PHASE(buf, 0, 0, VN, stageHT(s0));
    PHASE(buf, 0, 1, VN, stageHT(s0 + 1));
    PHASE(buf, 1, 0, VN, stageHT(s0 + 2));
    PHASE(buf, 1, 1, VN, stageHT(s0 + 3));
  }
  PHASE(0, 0, 0, VN, stageHT(126));
  PHASE(0, 0, 1, VN, stageHT(127));
  PHASE(0, 1, 0, VT1, (void)0);
  PHASE(0, 1, 1, VT2, (void)0);
  PHASE(1, 0, 0, VT3, (void)0);
  PHASE(1, 0, 1, 0, (void)0);
  PHASE(1, 1, 0, 0, (void)0);
  PHASE(1, 1, 1, 0, (void)0);
#undef PHASE

#pragma unroll
  for (int mig = 0; mig < 8; ++mig) {
#pragma unroll
    for (int j = 0; j < 4; ++j) {
      int row = m0 + wm * 128 + mig * 16 + lg * 4 + j;
#pragma unroll
      for (int ni = 0; ni < NF; ++ni) {
        int col = n0 + wn * (NF * 16) + ni * 16 + lr;
        float v = acc[mig][ni][j];
        if (F32OUT) ((float*)Cp)[(size_t)row * N + col] = v;
        else        ((unsigned short*)Cp)[(size_t)row * N + col] = f2b(v);
      }
    }
  }
}

// ---- fused K-RoPE (in place) + V transpose -> vt[b][kvh][d=64][t=1024] ----
__global__ __launch_bounds__(256)
void ropekv_kernel(unsigned short* __restrict__ qkv,
                   const float* __restrict__ cosb, const float* __restrict__ sinb,
                   unsigned short* __restrict__ vt) {
  const int tt0 = blockIdx.x * 64;
  const int kvh = blockIdx.y;
  const int b   = blockIdx.z;
  const int tid = threadIdx.x;

  // K RoPE: 64 rows x 64 cols; thread -> row tid>>2, col chunk (tid&3)*16 (8 pairs)
  {
    int r = tid >> 2, c0 = (tid & 3) * 16;
    int t = tt0 + r;
    unsigned short* kp = qkv + (size_t)(b * 1024 + t) * 3072 + 2048 + kvh * 64 + c0;
    const float* cb = cosb + t * 32 + c0 / 2;
    const float* sb = sinb + t * 32 + c0 / 2;
    ushort8v x0 = *(const ushort8v*)kp;
    ushort8v x1 = *(const ushort8v*)(kp + 8);
    float8v c = *(const float8v*)cb;
    float8v s = *(const float8v*)sb;
    ushort8v o0, o1;
#pragma unroll
    for (int j = 0; j < 4; ++j) {
      float xr = b2f(x0[2 * j]), xi = b2f(x0[2 * j + 1]);
      o0[2 * j]     = f2b(xr * c[j] - xi * s[j]);
      o0[2 * j + 1] = f2b(xr * s[j] + xi * c[j]);
    }
#pragma unroll
    for (int j = 0; j < 4; ++j) {
      float xr = b2f(x1[2 * j]), xi = b2f(x1[2 * j + 1]);
      o1[2 * j]     = f2b(xr * c[4 + j] - xi * s[4 + j]);
      o1[2 * j + 1] = f2b(xr * s[4 + j] + xi * c[4 + j]);
    }
    *(ushort8v*)kp = o0;
    *(ushort8v*)(kp + 8) = o1;
  }

  // V transpose via LDS
  __shared__ unsigned short lT[64 * 68];
#pragma unroll
  for (int i = 0; i < 2; ++i) {
    int r = i * 32 + (tid >> 3), c = (tid & 7) * 8;
    const unsigned short* src = qkv + (size_t)(b * 1024 + tt0 + r) * 3072 + 2560 + kvh * 64 + c;
    ushort8v v = *(const ushort8v*)src;
    ushort4v a, b4;
#pragma unroll
    for (int j = 0; j < 4; ++j) { a[j] = v[j]; b4[j] = v[j + 4]; }
    *(ushort4v*)&lT[r * 68 + c]     = a;
    *(ushort4v*)&lT[r * 68 + c + 4] = b4;
  }
  __syncthreads();
#pragma unroll
  for (int i = 0; i < 2; ++i) {
    int d = tid & 63;
    int tt = i * 4 + (tid >> 6);
    ushort8v o;
#pragma unroll
    for (int j = 0; j < 8; ++j) o[j] = lT[(tt * 8 + j) * 68 + d];
    *(ushort8v*)&vt[((size_t)((b * 8 + kvh) * 64 + d)) * 1024 + tt0 + tt * 8] = o;
  }
}

// ---- flash attention, swapped-operand 32x32 MFMA, paired q-tiles, KVBLK=128 ----
// grid (16,8,4) XCD-swizzled; block = (b,kvh, q-tile pair {bx, 31-bx}); 4 waves = 4 reps.
// 9 kv-tiles per block (perfectly balanced). Q-RoPE fused into the Q-fragment load.
__global__ __launch_bounds__(256, 2)
void attn_kernel(const unsigned short* __restrict__ qkv, const unsigned short* __restrict__ vt,
                 const float* __restrict__ cosb, const float* __restrict__ sinb,
                 unsigned short* __restrict__ ob) {
  // T1: chunked XCD swizzle (nwg=512, cpx=64): each XCD serves 4 (b,kvh) K/V streams
  const int flat = (blockIdx.z * 8 + blockIdx.y) * 16 + blockIdx.x;
  const int swzb = (flat & 7) * 64 + (flat >> 3);
  const int bx = swzb & 15, kvh = (swzb >> 4) & 7, b = swzb >> 7;

  const int tid = threadIdx.x, wave = tid >> 6, lane = tid & 63;
  const int l31 = lane & 31, hi = lane >> 5;
  const int h = kvh * 4 + wave;

  const int qth = 31 - bx, qtl = bx;
  const int q0h = qth * 32, q0l = qtl * 32;
  const int nth = qth / 4 + 1, ntl = qtl / 4 + 1;

  __shared__ unsigned short lK[2][128 * 64];
  __shared__ unsigned short lVt[2][64 * 128];

  // Q fragments with fused RoPE: lane holds Q[q0+l31][dk*16 + hi*8 + i]
  bf16x8 qfh[4], qfl[4];
  {
    auto ldq = [&](int q0, bf16x8* qf) {
      int t = q0 + l31;
      const unsigned short* qp = qkv + (size_t)(b * 1024 + t) * 3072 + h * 64;
#pragma unroll
      for (int dk = 0; dk < 4; ++dk) {
        ushort8v q = *(const ushort8v*)(qp + dk * 16 + hi * 8);
        f32x4 c4 = *(const f32x4*)(cosb + t * 32 + dk * 8 + hi * 4);
        f32x4 s4 = *(const f32x4*)(sinb + t * 32 + dk * 8 + hi * 4);
        ushort8v o;
#pragma unroll
        for (int j = 0; j < 4; ++j) {
          float xr = b2f(q[2 * j]), xi = b2f(q[2 * j + 1]);
          o[2 * j]     = f2b(xr * c4[j] - xi * s4[j]);
          o[2 * j + 1] = f2b(xr * s4[j] + xi * c4[j]);
        }
        qf[dk] = __builtin_bit_cast(bf16x8, o);
      }
    };
    ldq(q0h, qfh);
    ldq(q0l, qfl);
  }

  f32x16 oh[2] = {}, ol[2] = {};
  float mh = -3e38f, lh = 0.f, ml = -3e38f, ll = 0.f;

  const unsigned short* kg = qkv + (size_t)(b * 1024) * 3072 + 2048 + kvh * 64;
  const unsigned short* vg = vt + (size_t)(b * 8 + kvh) * 64 * 1024;

  auto stage = [&](int it, int bi) {
    const int kvb = it * 128;
    const int sr  = tid >> 3;          // 0..31
    const int scb = (tid & 7) * 16;    // K dest col byte
#pragma unroll
    for (int i = 0; i < 4; ++i) {
      int r = i * 32 + sr;
      int cb = scb ^ ((r & 7) << 4);
      async16(kg + (size_t)(kvb + r) * 3072 + (cb >> 1), &lK[bi][r * 64 + (scb >> 1)]);
    }
    const int rv0 = tid >> 4;          // 0..15
    const int scv = (tid & 15) * 16;   // V dest col byte
#pragma unroll
    for (int i = 0; i < 4; ++i) {
      int rv = i * 16 + rv0;
      int cbv = scv ^ ((rv & 15) << 4);
      async16(vg + (size_t)rv * 1024 + kvb + (cbv >> 1), &lVt[bi][rv * 128 + (scv >> 1)]);
    }
  };

  const float SC = 0.125f * 1.44269504f;
  // one q-state: S = K Q^T, online softmax, O += V^T P^T
  auto state = [&](int cur, int kvb, bf16x8 (&qf)[4], float& m2, float& l_run,
                   f32x16 (&oacc)[2], int q0, bool last) {
    f32x16 sd[4] = {};
    __builtin_amdgcn_s_setprio(1);
#pragma unroll
    for (int s = 0; s < 4; ++s) {
      const int krow = s * 32 + l31;
      const char* kr = (const char*)lK[cur] + krow * 128;
      const int swz = (krow & 7) << 4;
#pragma unroll
      for (int dk = 0; dk < 4; ++dk) {
        bf16x8 kf = *(const bf16x8*)(kr + ((dk * 32 + hi * 16) ^ swz));
        sd[s] = __builtin_amdgcn_mfma_f32_32x32x16_bf16(kf, qf[dk], sd[s], 0, 0, 0);
      }
    }
    __builtin_amdgcn_s_setprio(0);

#pragma unroll
    for (int s = 0; s < 4; ++s)
#pragma unroll
      for (int r = 0; r < 16; ++r) {
        float v = sd[s][r] * SC;
        if (last) {
          int kvg = kvb + s * 32 + (r & 3) + 8 * (r >> 2) + 4 * hi;
          if (kvg > q0 + l31) v = -3e38f;
        }
        sd[s][r] = v;
      }
    float pm = sd[0][0];
#pragma unroll
    for (int s = 0; s < 4; ++s)
#pragma unroll
      for (int r = 0; r < 16; ++r) pm = fmaxf(pm, sd[s][r]);
    pm = fmaxf(pm, __shfl_xor(pm, 32));
    if (!__all(pm <= m2 + 11.0f)) {          // T13 defer-max (log2 domain)
      float mnew = fmaxf(m2, pm);
      float alpha = exp2f(m2 - mnew);
      m2 = mnew;
      l_run *= alpha;
#pragma unroll
      for (int db = 0; db < 2; ++db)
#pragma unroll
        for (int r = 0; r < 16; ++r) oacc[db][r] *= alpha;
    }
    float tsum = 0.f;
#pragma unroll
    for (int s = 0; s < 4; ++s)
#pragma unroll
      for (int r = 0; r < 16; ++r) { float p = exp2f(sd[s][r] - m2); sd[s][r] = p; tsum += p; }
    tsum += __shfl_xor(tsum, 32);
    l_run += tsum;

    bf16x8 pf[4][2];
#pragma unroll
    for (int s = 0; s < 4; ++s)
#pragma unroll
      for (int kc = 0; kc < 2; ++kc) {
        unsigned int cA = cvtpk(sd[s][8 * kc + 0], sd[s][8 * kc + 1]);
        unsigned int cB = cvtpk(sd[s][8 * kc + 4], sd[s][8 * kc + 5]);
        unsigned int cC = cvtpk(sd[s][8 * kc + 2], sd[s][8 * kc + 3]);
        unsigned int cD = cvtpk(sd[s][8 * kc + 6], sd[s][8 * kc + 7]);
        unsigned int xA = __shfl_xor(cA, 32), xB = __shfl_xor(cB, 32);
        unsigned int xC = __shfl_xor(cC, 32), xD = __shfl_xor(cD, 32);
        uint4v u;
        u[0] = hi ? xB : cA;
        u[1] = hi ? xD : cC;
        u[2] = hi ? cB : xA;
        u[3] = hi ? cD : xC;
        pf[s][kc] = __builtin_bit_cast(bf16x8, u);
      }

    __builtin_amdgcn_s_setprio(1);
#pragma unroll
    for (int db = 0; db < 2; ++db) {
      const int row = db * 32 + l31;
      const char* vr = (const char*)lVt[cur] + row * 256;
      const int vswz = (row & 15) << 4;
#pragma unroll
      for (int s = 0; s < 4; ++s)
#pragma unroll
        for (int kc = 0; kc < 2; ++kc) {
          bf16x8 vf = *(const bf16x8*)(vr + ((s * 64 + kc * 32 + hi * 16) ^ vswz));
          oacc[db] = __builtin_amdgcn_mfma_f32_32x32x16_bf16(vf, pf[s][kc], oacc[db], 0, 0, 0);
        }
    }
    __builtin_amdgcn_s_setprio(0);
  };

  stage(0, 0);
  __syncthreads();

  for (int it = 0; it < nth; ++it) {
    const int cur = it & 1;
    if (it + 1 < nth) stage(it + 1, cur ^ 1);   // issue-early (T14)
    const int kvb = it * 128;

    state(cur, kvb, qfh, mh, lh, oh, q0h, it == nth - 1);
    if (it < ntl) state(cur, kvb, qfl, ml, ll, ol, q0l, it == ntl - 1);

    __syncthreads();   // drains prefetch + buffer handoff
  }

  // epilogue: O^T row r -> d = (r&3)+8*(r>>2)+4*hi, col = q = l31
  {
    float inv = 1.0f / lh;
    unsigned short* orow = ob + (size_t)(b * 1024 + q0h + l31) * 2048 + h * 64;
#pragma unroll
    for (int db = 0; db < 2; ++db)
#pragma unroll
      for (int g = 0; g < 4; ++g) {
        int d0 = db * 32 + 8 * g + 4 * hi;
        ushort4v o;
#pragma unroll
        for (int j = 0; j < 4; ++j) o[j] = f2b(oh[db][4 * g + j] * inv);
        *(ushort4v*)(orow + d0) = o;
      }
  }
  {
    float inv = 1.0f / ll;
    unsigned short* orow = ob + (size_t)(b * 1024 + q0l + l31) * 2048 + h * 64;
#pragma unroll
    for (int db = 0; db < 2; ++db)
#pragma unroll
      for (int g = 0; g < 4; ++g) {
        int d0 = db * 32 + 8 * g + 4 * hi;
        ushort4v o;
#pragma unroll
        for (int j = 0; j < 4; ++j) o[j] = f2b(ol[db][4 * g + j] * inv);
        *(ushort4v*)(orow + d0) = o;
      }
  }
}

extern "C" void kernel_launch(void* const* d_in, const int* in_sizes, int n_in,
                              void* d_out, int out_size, void* d_ws, size_t ws_size,
                              hipStream_t stream) {
  const float* input = (const float*)d_in[0];
  const float* fcos  = (const float*)d_in[1];
  const float* fsin  = (const float*)d_in[2];
  const float* wq = (const float*)d_in[4];
  const float* wk = (const float*)d_in[5];
  const float* wv = (const float*)d_in[6];
  const float* wo = (const float*)d_in[7];
  float* out = (float*)d_out;

  unsigned short* xb   = (unsigned short*)d_ws;               // 4096 x 2048 (dead after gemm1)
  unsigned short* wqkv = xb + (size_t)4096 * 2048;            // 3072 x 2048
  unsigned short* wob  = wqkv + (size_t)3072 * 2048;          // 2048 x 2048
  unsigned short* qkv  = wob + (size_t)2048 * 2048;           // 4096 x 3072
  unsigned short* ob   = qkv + (size_t)4096 * 3072;           // 4096 x 2048
  unsigned short* vtb  = xb;                                  // 4*8*64*1024 (reuses xb)

  hipFuncSetAttribute((const void*)&gemm8p<false, 256, 12>,
                      hipFuncAttributeMaxDynamicSharedMemorySize, 131072);
  hipFuncSetAttribute((const void*)&gemm8p<true, 128, 16>,
                      hipFuncAttributeMaxDynamicSharedMemorySize, 98304);

  CvtArgs ca;
  ca.src[0] = input; ca.dst[0] = xb;                        ca.n[0] = (long)4096 * 2048;
  ca.src[1] = wq;    ca.dst[1] = wqkv;                      ca.n[1] = (long)2048 * 2048;
  ca.src[2] = wk;    ca.dst[2] = wqkv + (size_t)2048 * 2048; ca.n[2] = (long)512 * 2048;
  ca.src[3] = wv;    ca.dst[3] = wqkv + (size_t)2560 * 2048; ca.n[3] = (long)512 * 2048;
  ca.src[4] = wo;    ca.dst[4] = wob;                       ca.n[4] = (long)2048 * 2048;
  hipLaunchKernelGGL(cvt5_kernel, dim3(2048), dim3(256), 0, stream, ca);

  // fused QKV projection: qkv = xb @ wqkv^T  (M=4096, N=3072, K=2048)
  hipLaunchKernelGGL((gemm8p<false, 256, 12>), dim3(12, 16), dim3(512), 131072,
                     stream, xb, wqkv, (void*)qkv, 4096, 3072);

  // K-RoPE in place + V transpose
  hipLaunchKernelGGL(ropekv_kernel, dim3(16, 8, 4), dim3(256), 0, stream,
                     qkv, fcos, fsin, vtb);

  // flash attention (Q-RoPE fused) -> ob (b,t,h,d) bf16
  hipLaunchKernelGGL(attn_kernel, dim3(16, 8, 4), dim3(256), 0, stream,
                     qkv, vtb, fcos, fsin, ob);

  // output projection: out = ob @ wob^T  (M=4096, N=2048, K=2048), fp32 out
  hipLaunchKernelGGL((gemm8p<true, 128, 16>), dim3(16, 16), dim3(512), 98304,
                     stream, ob, wob, (void*)out, 4096, 2048);
}

// Round 6
// 171.206 us; speedup vs baseline: 1.9110x; 1.0824x over previous
//
#include <hip/hip_runtime.h>
#include <cstdint>

// ---- types ----
typedef __bf16 bf16x8 __attribute__((ext_vector_type(8)));
typedef float  f32x4  __attribute__((ext_vector_type(4)));
typedef float  f32x16 __attribute__((ext_vector_type(16)));
typedef float  float8v __attribute__((ext_vector_type(8)));
typedef unsigned short ushort8v __attribute__((ext_vector_type(8)));
typedef unsigned short ushort4v __attribute__((ext_vector_type(4)));
typedef unsigned int   uint4v   __attribute__((ext_vector_type(4)));

__device__ __forceinline__ unsigned short f2b(float f) {
  uint32_t u = __builtin_bit_cast(uint32_t, f);
  u += 0x7FFFu + ((u >> 16) & 1u);     // round-to-nearest-even
  return (unsigned short)(u >> 16);
}
__device__ __forceinline__ float b2f(unsigned short h) {
  uint32_t u = ((uint32_t)h) << 16;
  return __builtin_bit_cast(float, u);
}
__device__ __forceinline__ unsigned int cvtpk(float lo, float hi_) {
  unsigned int r;
  asm("v_cvt_pk_bf16_f32 %0, %1, %2" : "=v"(r) : "v"(lo), "v"(hi_));
  return r;
}

__device__ __forceinline__ void async16(const void* g, void* l) {
  __builtin_amdgcn_global_load_lds(
      (const __attribute__((address_space(1))) void*)g,
      (__attribute__((address_space(3))) void*)l, 16, 0, 0);
}

// s_waitcnt immediates (gfx9 encoding): vmcnt[3:0]|[15:14], expcnt[6:4], lgkmcnt[11:8]
#define WAITVM(N)  __builtin_amdgcn_s_waitcnt(0x0F70 | ((N) & 15))
#define WAITLGKM0  __builtin_amdgcn_s_waitcnt(0xC07F)

// ---- fused fp32 -> bf16 convert, 5 segments in one launch ----
struct CvtArgs {
  const float* src[5];
  unsigned short* dst[5];
  long n[5];
};
__global__ void cvt5_kernel(CvtArgs a) {
  long base = (long)blockIdx.x * blockDim.x + threadIdx.x;
  long gstride = (long)gridDim.x * blockDim.x;
#pragma unroll 1
  for (int sg = 0; sg < 5; ++sg) {
    const float* s = a.src[sg];
    unsigned short* d = a.dst[sg];
    long n8 = a.n[sg] >> 3;
    for (long i = base; i < n8; i += gstride) {
      float8v f = *(const float8v*)(s + i * 8);
      ushort8v o;
#pragma unroll
      for (int j = 0; j < 8; ++j) o[j] = f2b(f[j]);
      *(ushort8v*)(d + i * 8) = o;
    }
  }
}

// ---- 8-phase 256-row GEMM: C[M][N] = A[M][K] * W[N][K]^T, K=2048, M=4096 ----
template<bool F32OUT, int BN, int GX>
__global__ __launch_bounds__(512, 1)
void gemm8p(const unsigned short* __restrict__ Ag, const unsigned short* __restrict__ Wg,
            void* __restrict__ Cp, int M, int N) {
  constexpr int K = 2048;
  constexpr int NF = BN / 64;
  constexpr int BL = BN / 128;
  constexpr int VN = 4 + 2 * BL;
  constexpr int VT1 = (BN == 256) ? 6 : 4;
  constexpr int VT2 = (BN == 256) ? 4 : 3;
  constexpr int VT3 = (BN == 256) ? 2 : 1;
  constexpr int ASLOT = 16384;
  constexpr int BSLOT = BN * 64;
  constexpr int CPX = 2 * GX;

  extern __shared__ char lds_c[];

  const int tid = threadIdx.x;
  const int wave = tid >> 6, lane = tid & 63;
  const int wm = wave >> 2, wn = wave & 3;
  const int lr = lane & 15, lg = lane >> 4;

  const int flat = blockIdx.y * GX + blockIdx.x;
  const int swz = (flat & 7) * CPX + (flat >> 3);
  const int m0 = (swz / GX) * 256, n0 = (swz % GX) * BN;

  const int laneSw = (lr >> 1) * 128 + (((((lr & 1) << 2) | lg) ^ (lr >> 1)) << 4);
  const int aoff = wm * 8192 + laneSw;
  const int boff = wn * NF * 1024 + laneSw;

  f32x4 acc[8][NF] = {};

  auto stageHT = [&](int s) {
    const int ty = s & 3;
    const int kh = (s >> 1) & 1;
    const int buf = (s >> 2) & 1;
    const int kc = (s >> 2) * 64 + kh * 32;
    if (ty == 0 || ty == 2) {
      char* slot = lds_c + (buf * 2 + kh) * ASLOT;
#pragma unroll
      for (int j = 0; j < 2; ++j) {
        int q = (tid + 512 * j) * 16;
        int R = q >> 7, g2L = ((q >> 4) & 7) ^ (R & 7);
        int row = R * 2 + (g2L >> 2), kg = g2L & 3;
        async16(Ag + (size_t)(m0 + row) * K + kc + kg * 8, slot + q);
      }
    } else {
      char* slot = lds_c + 65536 + (buf * 2 + kh) * BSLOT;
#pragma unroll
      for (int j = 0; j < BL; ++j) {
        int q = (tid + 512 * j) * 16;
        int R = q >> 7, g2L = ((q >> 4) & 7) ^ (R & 7);
        int row = R * 2 + (g2L >> 2), kg = g2L & 3;
        async16(Wg + (size_t)(n0 + row) * K + kc + kg * 8, slot + q);
      }
    }
  };

#define PHASE(BUF, KH, MH, VM, ...)                                           \
  {                                                                           \
    const char* As_ = lds_c + ((BUF) * 2 + (KH)) * ASLOT;                     \
    const char* Bs_ = lds_c + 65536 + ((BUF) * 2 + (KH)) * BSLOT;             \
    bf16x8 af_[4], bf_[NF];                                                   \
    _Pragma("unroll") for (int mi = 0; mi < 4; ++mi)                          \
      af_[mi] = *(const bf16x8*)(As_ + aoff + (MH) * 4096 + mi * 1024);       \
    _Pragma("unroll") for (int ni = 0; ni < NF; ++ni)                         \
      bf_[ni] = *(const bf16x8*)(Bs_ + boff + ni * 1024);                     \
    __VA_ARGS__;                                                              \
    WAITVM(VM);                                                               \
    __builtin_amdgcn_s_barrier();                                             \
    WAITLGKM0;                                                                \
    __builtin_amdgcn_sched_barrier(0);                                        \
    __builtin_amdgcn_s_setprio(1);                                            \
    _Pragma("unroll") for (int mi = 0; mi < 4; ++mi)                          \
      _Pragma("unroll") for (int ni = 0; ni < NF; ++ni)                       \
        acc[(MH) * 4 + mi][ni] = __builtin_amdgcn_mfma_f32_16x16x32_bf16(     \
            af_[mi], bf_[ni], acc[(MH) * 4 + mi][ni], 0, 0, 0);               \
    __builtin_amdgcn_s_setprio(0);                                            \
    __builtin_amdgcn_s_barrier();                                             \
  }

#pragma unroll
  for (int s = 0; s < 6; ++s) stageHT(s);
  WAITVM(VN);
  __builtin_amdgcn_s_barrier();

#pragma unroll 2
  for (int kt = 0; kt < 30; ++kt) {
    const int buf = kt & 1;
    const int s0 = kt * 4 + 6;
    PHASE(buf, 0, 0, VN, stageHT(s0));
    PHASE(buf, 0, 1, VN, stageHT(s0 + 1));
    PHASE(buf, 1, 0, VN, stageHT(s0 + 2));
    PHASE(buf, 1, 1, VN, stageHT(s0 + 3));
  }
  PHASE(0, 0, 0, VN, stageHT(126));
  PHASE(0, 0, 1, VN, stageHT(127));
  PHASE(0, 1, 0, VT1, (void)0);
  PHASE(0, 1, 1, VT2, (void)0);
  PHASE(1, 0, 0, VT3, (void)0);
  PHASE(1, 0, 1, 0, (void)0);
  PHASE(1, 1, 0, 0, (void)0);
  PHASE(1, 1, 1, 0, (void)0);
#undef PHASE

#pragma unroll
  for (int mig = 0; mig < 8; ++mig) {
#pragma unroll
    for (int j = 0; j < 4; ++j) {
      int row = m0 + wm * 128 + mig * 16 + lg * 4 + j;
#pragma unroll
      for (int ni = 0; ni < NF; ++ni) {
        int col = n0 + wn * (NF * 16) + ni * 16 + lr;
        float v = acc[mig][ni][j];
        if (F32OUT) ((float*)Cp)[(size_t)row * N + col] = v;
        else        ((unsigned short*)Cp)[(size_t)row * N + col] = f2b(v);
      }
    }
  }
}

// ---- fused K-RoPE (in place) + V transpose -> vt[b][kvh][d=64][t=1024] ----
__global__ __launch_bounds__(256)
void ropekv_kernel(unsigned short* __restrict__ qkv,
                   const float* __restrict__ cosb, const float* __restrict__ sinb,
                   unsigned short* __restrict__ vt) {
  const int tt0 = blockIdx.x * 64;
  const int kvh = blockIdx.y;
  const int b   = blockIdx.z;
  const int tid = threadIdx.x;

  {
    int r = tid >> 2, c0 = (tid & 3) * 16;
    int t = tt0 + r;
    unsigned short* kp = qkv + (size_t)(b * 1024 + t) * 3072 + 2048 + kvh * 64 + c0;
    const float* cb = cosb + t * 32 + c0 / 2;
    const float* sb = sinb + t * 32 + c0 / 2;
    ushort8v x0 = *(const ushort8v*)kp;
    ushort8v x1 = *(const ushort8v*)(kp + 8);
    float8v c = *(const float8v*)cb;
    float8v s = *(const float8v*)sb;
    ushort8v o0, o1;
#pragma unroll
    for (int j = 0; j < 4; ++j) {
      float xr = b2f(x0[2 * j]), xi = b2f(x0[2 * j + 1]);
      o0[2 * j]     = f2b(xr * c[j] - xi * s[j]);
      o0[2 * j + 1] = f2b(xr * s[j] + xi * c[j]);
    }
#pragma unroll
    for (int j = 0; j < 4; ++j) {
      float xr = b2f(x1[2 * j]), xi = b2f(x1[2 * j + 1]);
      o1[2 * j]     = f2b(xr * c[4 + j] - xi * s[4 + j]);
      o1[2 * j + 1] = f2b(xr * s[4 + j] + xi * c[4 + j]);
    }
    *(ushort8v*)kp = o0;
    *(ushort8v*)(kp + 8) = o1;
  }

  __shared__ unsigned short lT[64 * 68];
#pragma unroll
  for (int i = 0; i < 2; ++i) {
    int r = i * 32 + (tid >> 3), c = (tid & 7) * 8;
    const unsigned short* src = qkv + (size_t)(b * 1024 + tt0 + r) * 3072 + 2560 + kvh * 64 + c;
    ushort8v v = *(const ushort8v*)src;
    ushort4v a, b4;
#pragma unroll
    for (int j = 0; j < 4; ++j) { a[j] = v[j]; b4[j] = v[j + 4]; }
    *(ushort4v*)&lT[r * 68 + c]     = a;
    *(ushort4v*)&lT[r * 68 + c + 4] = b4;
  }
  __syncthreads();
#pragma unroll
  for (int i = 0; i < 2; ++i) {
    int d = tid & 63;
    int tt = i * 4 + (tid >> 6);
    ushort8v o;
#pragma unroll
    for (int j = 0; j < 8; ++j) o[j] = lT[(tt * 8 + j) * 68 + d];
    *(ushort8v*)&vt[((size_t)((b * 8 + kvh) * 64 + d)) * 1024 + tt0 + tt * 8] = o;
  }
}

// ---- flash attention: paired q-tiles processed SEQUENTIALLY (one live state) ----
// grid (16,8,4) XCD-swizzled. Block = (b,kvh, pair {31-bx, bx}), 4 waves = 4 reps.
// KVBLK=128 staged (dbuf, issue-early), computed in 64-kv chunks (sd[2] only).
// Exactly 9 staged tiles per block. Q-RoPE fused into Q-fragment load.
__global__ __launch_bounds__(256, 2)
void attn_kernel(const unsigned short* __restrict__ qkv, const unsigned short* __restrict__ vt,
                 const float* __restrict__ cosb, const float* __restrict__ sinb,
                 unsigned short* __restrict__ ob) {
  const int flat = (blockIdx.z * 8 + blockIdx.y) * 16 + blockIdx.x;
  const int swzb = (flat & 7) * 64 + (flat >> 3);
  const int bx = swzb & 15, kvh = (swzb >> 4) & 7, b = swzb >> 7;

  const int tid = threadIdx.x, wave = tid >> 6, lane = tid & 63;
  const int l31 = lane & 31, hi = lane >> 5;
  const int h = kvh * 4 + wave;

  const int qth = 31 - bx, qtl = bx;
  const int q0h = qth * 32, q0l = qtl * 32;
  const int nth = qth / 4 + 1, ntl = qtl / 4 + 1;
  const int ntot = nth + ntl;

  __shared__ unsigned short lK[2][128 * 64];
  __shared__ unsigned short lVt[2][64 * 128];

  // Q fragment load with fused RoPE: lane holds Q[q0+l31][dk*16 + hi*8 + i]
  auto ldq = [&](int q0, bf16x8* qf) {
    int t = q0 + l31;
    const unsigned short* qp = qkv + (size_t)(b * 1024 + t) * 3072 + h * 64;
#pragma unroll
    for (int dk = 0; dk < 4; ++dk) {
      ushort8v q = *(const ushort8v*)(qp + dk * 16 + hi * 8);
      f32x4 c4 = *(const f32x4*)(cosb + t * 32 + dk * 8 + hi * 4);
      f32x4 s4 = *(const f32x4*)(sinb + t * 32 + dk * 8 + hi * 4);
      ushort8v o;
#pragma unroll
      for (int j = 0; j < 4; ++j) {
        float xr = b2f(q[2 * j]), xi = b2f(q[2 * j + 1]);
        o[2 * j]     = f2b(xr * c4[j] - xi * s4[j]);
        o[2 * j + 1] = f2b(xr * s4[j] + xi * c4[j]);
      }
      qf[dk] = __builtin_bit_cast(bf16x8, o);
    }
  };

  const unsigned short* kg = qkv + (size_t)(b * 1024) * 3072 + 2048 + kvh * 64;
  const unsigned short* vg = vt + (size_t)(b * 8 + kvh) * 64 * 1024;

  auto stage = [&](int kvb, int bi) {
    const int sr  = tid >> 3;
    const int scb = (tid & 7) * 16;
#pragma unroll
    for (int i = 0; i < 4; ++i) {
      int r = i * 32 + sr;
      int cb = scb ^ ((r & 7) << 4);
      async16(kg + (size_t)(kvb + r) * 3072 + (cb >> 1), &lK[bi][r * 64 + (scb >> 1)]);
    }
    const int rv0 = tid >> 4;
    const int scv = (tid & 15) * 16;
#pragma unroll
    for (int i = 0; i < 4; ++i) {
      int rv = i * 16 + rv0;
      int cbv = scv ^ ((rv & 15) << 4);
      async16(vg + (size_t)rv * 1024 + kvb + (cbv >> 1), &lVt[bi][rv * 128 + (scv >> 1)]);
    }
  };

  // single live state
  bf16x8 qf[4];
  f32x16 oacc[2] = {};
  float m2 = -3e38f, l_run = 0.f;
  int q0 = q0h;

  ldq(q0h, qf);

  const float SC = 0.125f * 1.44269504f;

  // one 64-kv chunk: S = K Q^T, online softmax, O += V^T P^T
  auto chunk64 = [&](int cur, int ckvb, int c, bool lastT) {
    f32x16 sd[2] = {};
    __builtin_amdgcn_s_setprio(1);
#pragma unroll
    for (int s = 0; s < 2; ++s) {
      const int krow = c * 64 + s * 32 + l31;
      const char* kr = (const char*)lK[cur] + krow * 128;
      const int swz = (krow & 7) << 4;
#pragma unroll
      for (int dk = 0; dk < 4; ++dk) {
        bf16x8 kf = *(const bf16x8*)(kr + ((dk * 32 + hi * 16) ^ swz));
        sd[s] = __builtin_amdgcn_mfma_f32_32x32x16_bf16(kf, qf[dk], sd[s], 0, 0, 0);
      }
    }
    __builtin_amdgcn_s_setprio(0);

#pragma unroll
    for (int s = 0; s < 2; ++s)
#pragma unroll
      for (int r = 0; r < 16; ++r) {
        float v = sd[s][r] * SC;
        if (lastT) {
          int kvg = ckvb + s * 32 + (r & 3) + 8 * (r >> 2) + 4 * hi;
          if (kvg > q0 + l31) v = -3e38f;
        }
        sd[s][r] = v;
      }
    float pm = sd[0][0];
#pragma unroll
    for (int s = 0; s < 2; ++s)
#pragma unroll
      for (int r = 0; r < 16; ++r) pm = fmaxf(pm, sd[s][r]);
    pm = fmaxf(pm, __shfl_xor(pm, 32));
    if (!__all(pm <= m2 + 11.0f)) {          // T13 defer-max (log2 domain)
      float mnew = fmaxf(m2, pm);
      float alpha = exp2f(m2 - mnew);
      m2 = mnew;
      l_run *= alpha;
#pragma unroll
      for (int db = 0; db < 2; ++db)
#pragma unroll
        for (int r = 0; r < 16; ++r) oacc[db][r] *= alpha;
    }
    float tsum = 0.f;
#pragma unroll
    for (int s = 0; s < 2; ++s)
#pragma unroll
      for (int r = 0; r < 16; ++r) { float p = exp2f(sd[s][r] - m2); sd[s][r] = p; tsum += p; }
    tsum += __shfl_xor(tsum, 32);
    l_run += tsum;

    bf16x8 pf[2][2];
#pragma unroll
    for (int s = 0; s < 2; ++s)
#pragma unroll
      for (int kc = 0; kc < 2; ++kc) {
        unsigned int cA = cvtpk(sd[s][8 * kc + 0], sd[s][8 * kc + 1]);
        unsigned int cB = cvtpk(sd[s][8 * kc + 4], sd[s][8 * kc + 5]);
        unsigned int cC = cvtpk(sd[s][8 * kc + 2], sd[s][8 * kc + 3]);
        unsigned int cD = cvtpk(sd[s][8 * kc + 6], sd[s][8 * kc + 7]);
        unsigned int xA = __shfl_xor(cA, 32), xB = __shfl_xor(cB, 32);
        unsigned int xC = __shfl_xor(cC, 32), xD = __shfl_xor(cD, 32);
        uint4v u;
        u[0] = hi ? xB : cA;
        u[1] = hi ? xD : cC;
        u[2] = hi ? cB : xA;
        u[3] = hi ? cD : xC;
        pf[s][kc] = __builtin_bit_cast(bf16x8, u);
      }

    __builtin_amdgcn_s_setprio(1);
#pragma unroll
    for (int db = 0; db < 2; ++db) {
      const int row = db * 32 + l31;
      const char* vr = (const char*)lVt[cur] + row * 256;
      const int vswz = (row & 15) << 4;
#pragma unroll
      for (int s = 0; s < 2; ++s)
#pragma unroll
        for (int kc = 0; kc < 2; ++kc) {
          bf16x8 vf = *(const bf16x8*)(vr + ((c * 128 + s * 64 + kc * 32 + hi * 16) ^ vswz));
          oacc[db] = __builtin_amdgcn_mfma_f32_32x32x16_bf16(vf, pf[s][kc], oacc[db], 0, 0, 0);
        }
    }
    __builtin_amdgcn_s_setprio(0);
  };

  auto writeOut = [&](int q0w) {
    float inv = 1.0f / l_run;
    unsigned short* orow = ob + (size_t)(b * 1024 + q0w + l31) * 2048 + h * 64;
#pragma unroll
    for (int db = 0; db < 2; ++db)
#pragma unroll
      for (int g = 0; g < 4; ++g) {
        int d0 = db * 32 + 8 * g + 4 * hi;
        ushort4v o;
#pragma unroll
        for (int j = 0; j < 4; ++j) o[j] = f2b(oacc[db][4 * g + j] * inv);
        *(ushort4v*)(orow + d0) = o;
      }
  };

  auto kvb_of = [&](int j) { return (j < nth ? j : j - nth) * 128; };

  stage(0, 0);
  __syncthreads();

  for (int j = 0; j < ntot; ++j) {
    const int cur = j & 1;
    if (j + 1 < ntot) stage(kvb_of(j + 1), cur ^ 1);   // issue-early (T14)
    const int kvb = kvb_of(j);
    const bool lastT = (j == nth - 1) || (j == ntot - 1);

#pragma unroll 1
    for (int c = 0; c < 2; ++c) {
      if (kvb + c * 64 > q0 + 31) continue;   // fully-masked chunk (uniform)
      chunk64(cur, kvb + c * 64, c, lastT);
    }

    if (j == nth - 1) {                        // hi pass done -> switch to lo
      writeOut(q0h);
      oacc[0] = f32x16{}; oacc[1] = f32x16{};
      m2 = -3e38f; l_run = 0.f;
      q0 = q0l;
      ldq(q0l, qf);
    }
    __syncthreads();   // drains prefetch + buffer handoff
  }
  writeOut(q0l);
}

extern "C" void kernel_launch(void* const* d_in, const int* in_sizes, int n_in,
                              void* d_out, int out_size, void* d_ws, size_t ws_size,
                              hipStream_t stream) {
  const float* input = (const float*)d_in[0];
  const float* fcos  = (const float*)d_in[1];
  const float* fsin  = (const float*)d_in[2];
  const float* wq = (const float*)d_in[4];
  const float* wk = (const float*)d_in[5];
  const float* wv = (const float*)d_in[6];
  const float* wo = (const float*)d_in[7];
  float* out = (float*)d_out;

  unsigned short* xb   = (unsigned short*)d_ws;               // 4096 x 2048 (dead after gemm1)
  unsigned short* wqkv = xb + (size_t)4096 * 2048;            // 3072 x 2048
  unsigned short* wob  = wqkv + (size_t)3072 * 2048;          // 2048 x 2048
  unsigned short* qkv  = wob + (size_t)2048 * 2048;           // 4096 x 3072
  unsigned short* ob   = qkv + (size_t)4096 * 3072;           // 4096 x 2048
  unsigned short* vtb  = xb;                                  // 4*8*64*1024 (reuses xb)

  hipFuncSetAttribute((const void*)&gemm8p<false, 256, 12>,
                      hipFuncAttributeMaxDynamicSharedMemorySize, 131072);
  hipFuncSetAttribute((const void*)&gemm8p<true, 128, 16>,
                      hipFuncAttributeMaxDynamicSharedMemorySize, 98304);

  CvtArgs ca;
  ca.src[0] = input; ca.dst[0] = xb;                        ca.n[0] = (long)4096 * 2048;
  ca.src[1] = wq;    ca.dst[1] = wqkv;                      ca.n[1] = (long)2048 * 2048;
  ca.src[2] = wk;    ca.dst[2] = wqkv + (size_t)2048 * 2048; ca.n[2] = (long)512 * 2048;
  ca.src[3] = wv;    ca.dst[3] = wqkv + (size_t)2560 * 2048; ca.n[3] = (long)512 * 2048;
  ca.src[4] = wo;    ca.dst[4] = wob;                       ca.n[4] = (long)2048 * 2048;
  hipLaunchKernelGGL(cvt5_kernel, dim3(2048), dim3(256), 0, stream, ca);

  // fused QKV projection: qkv = xb @ wqkv^T  (M=4096, N=3072, K=2048)
  hipLaunchKernelGGL((gemm8p<false, 256, 12>), dim3(12, 16), dim3(512), 131072,
                     stream, xb, wqkv, (void*)qkv, 4096, 3072);

  // K-RoPE in place + V transpose
  hipLaunchKernelGGL(ropekv_kernel, dim3(16, 8, 4), dim3(256), 0, stream,
                     qkv, fcos, fsin, vtb);

  // flash attention (Q-RoPE fused) -> ob (b,t,h,d) bf16
  hipLaunchKernelGGL(attn_kernel, dim3(16, 8, 4), dim3(256), 0, stream,
                     qkv, vtb, fcos, fsin, ob);

  // output projection: out = ob @ wob^T  (M=4096, N=2048, K=2048), fp32 out
  hipLaunchKernelGGL((gemm8p<true, 128, 16>), dim3(16, 16), dim3(512), 98304,
                     stream, ob, wob, (void*)out, 4096, 2048);
}